// Round 1
// baseline (4923.183 us; speedup 1.0000x reference)
//
#include <hip/hip_runtime.h>

// ---------------- constants ----------------
namespace {
constexpr int Bn   = 2;
constexpr int Cc   = 256;
constexpr int Nh   = 8;
constexpr int Dh   = 32;
constexpr int Ntok = 5376;      // 4096 + 1024 + 256
constexpr int Ffn  = 1024;
constexpr int HW2  = 128 * 128; // res2 spatial
constexpr float EPSf = 1e-5f;
}

// ---------------- positional encoding ----------------
__global__ void pe_kernel(float* __restrict__ pe) {
  for (int i = blockIdx.x * blockDim.x + threadIdx.x; i < Ntok * Cc;
       i += gridDim.x * blockDim.x) {
    int c = i & 255;
    int p = i >> 8;
    int li = (p < 4096) ? 0 : ((p < 5120) ? 1 : 2);
    int start = (li == 0) ? 0 : ((li == 1) ? 4096 : 5120);
    int W = 64 >> li;
    int sp = p - start;
    int shift = 6 - li;
    int iy = sp >> shift;
    int ix = sp & (W - 1);
    int j = c & 63;
    int sel = c >> 6;
    float div = expf(-(float)j * (9.210340371976184f / 64.f)); // ln(1e4)/64
    float coord = (sel < 2) ? (float)iy : (float)ix;
    float arg = coord * div;
    pe[i] = (sel & 1) ? cosf(arg) : sinf(arg);
  }
}

// ---------------- flatten + level_embed ----------------
__global__ void flatten_kernel(const float* __restrict__ r3,
                               const float* __restrict__ r4,
                               const float* __restrict__ r5,
                               const float* __restrict__ lemb,
                               float* __restrict__ x) {
  for (int i = blockIdx.x * blockDim.x + threadIdx.x; i < Bn * Ntok * Cc;
       i += gridDim.x * blockDim.x) {
    int c = i & 255;
    int rest = i >> 8;
    int p = rest % Ntok;
    int b = rest / Ntok;
    int li = (p < 4096) ? 0 : ((p < 5120) ? 1 : 2);
    int start = (li == 0) ? 0 : ((li == 1) ? 4096 : 5120);
    int size = (li == 0) ? 4096 : ((li == 1) ? 1024 : 256);
    const float* f = (li == 0) ? r3 : ((li == 1) ? r4 : r5);
    int sp = p - start;
    x[i] = f[((size_t)(b * Cc + c)) * size + sp] + lemb[li * Cc + c];
  }
}

// ---------------- q = x + pe ----------------
__global__ void addpe_kernel(const float* __restrict__ x,
                             const float* __restrict__ pe,
                             float* __restrict__ q) {
  const int NPC = Ntok * Cc;
  for (int i = blockIdx.x * blockDim.x + threadIdx.x; i < Bn * NPC;
       i += gridDim.x * blockDim.x) {
    int pc = (i >= NPC) ? i - NPC : i;
    q[i] = x[i] + pe[pc];
  }
}

// ---------------- generic GEMM: out = A(M,K) @ W(N,K)^T + bias ----------------
__global__ __launch_bounds__(256) void gemm_bias(
    const float* __restrict__ A, const float* __restrict__ W,
    const float* __restrict__ bias, float* __restrict__ out,
    int M, int N, int K, int act) {
  __shared__ float As[16][65];
  __shared__ float Ws[16][65];
  const int tid = threadIdx.x;
  const int tx = tid & 15, ty = tid >> 4;
  const int m0 = blockIdx.y * 64, n0 = blockIdx.x * 64;
  float acc[4][4] = {{0.f}};
  for (int k0 = 0; k0 < K; k0 += 16) {
#pragma unroll
    for (int i = 0; i < 4; i++) {
      int idx = tid + i * 256;
      int r = idx >> 4, kk = idx & 15;
      int m = m0 + r;
      As[kk][r] = (m < M) ? A[(size_t)m * K + k0 + kk] : 0.f;
      int n = n0 + r;
      Ws[kk][r] = (n < N) ? W[(size_t)n * K + k0 + kk] : 0.f;
    }
    __syncthreads();
#pragma unroll
    for (int kk = 0; kk < 16; kk++) {
      float a0 = As[kk][ty * 4 + 0], a1 = As[kk][ty * 4 + 1];
      float a2 = As[kk][ty * 4 + 2], a3 = As[kk][ty * 4 + 3];
      float b0 = Ws[kk][tx * 4 + 0], b1 = Ws[kk][tx * 4 + 1];
      float b2 = Ws[kk][tx * 4 + 2], b3 = Ws[kk][tx * 4 + 3];
      acc[0][0] += a0 * b0; acc[0][1] += a0 * b1; acc[0][2] += a0 * b2; acc[0][3] += a0 * b3;
      acc[1][0] += a1 * b0; acc[1][1] += a1 * b1; acc[1][2] += a1 * b2; acc[1][3] += a1 * b3;
      acc[2][0] += a2 * b0; acc[2][1] += a2 * b1; acc[2][2] += a2 * b2; acc[2][3] += a2 * b3;
      acc[3][0] += a3 * b0; acc[3][1] += a3 * b1; acc[3][2] += a3 * b2; acc[3][3] += a3 * b3;
    }
    __syncthreads();
  }
#pragma unroll
  for (int i = 0; i < 4; i++) {
    int m = m0 + ty * 4 + i;
    if (m >= M) continue;
#pragma unroll
    for (int j = 0; j < 4; j++) {
      int n = n0 + tx * 4 + j;
      if (n >= N) continue;
      float v = acc[i][j] + bias[n];
      if (act == 1) v = fmaxf(v, 0.f);
      out[(size_t)m * N + n] = v;
    }
  }
}

// ------------- TN GEMM for 1x1 lateral conv: A=(B,K,HW) NCHW, out=(B,HW,N) -------------
__global__ __launch_bounds__(256) void gemm_tn_bias(
    const float* __restrict__ A, const float* __restrict__ W,
    const float* __restrict__ bias, float* __restrict__ out,
    int HW, int K, int N) {
  __shared__ float As[16][65];
  __shared__ float Ws[16][65];
  const int tid = threadIdx.x;
  const int tx = tid & 15, ty = tid >> 4;
  const int m0 = blockIdx.y * 64, n0 = blockIdx.x * 64;
  const int b = m0 / HW;
  const int p0 = m0 % HW;
  float acc[4][4] = {{0.f}};
  for (int k0 = 0; k0 < K; k0 += 16) {
#pragma unroll
    for (int i = 0; i < 4; i++) {
      int idx = tid + i * 256;
      {
        int r = idx & 63, kk = idx >> 6;
        As[kk][r] = A[((size_t)(b * K + k0 + kk)) * HW + p0 + r];
      }
      {
        int r = idx >> 4, kk = idx & 15;
        Ws[kk][r] = W[(size_t)(n0 + r) * K + k0 + kk];
      }
    }
    __syncthreads();
#pragma unroll
    for (int kk = 0; kk < 16; kk++) {
      float a0 = As[kk][ty * 4 + 0], a1 = As[kk][ty * 4 + 1];
      float a2 = As[kk][ty * 4 + 2], a3 = As[kk][ty * 4 + 3];
      float b0 = Ws[kk][tx * 4 + 0], b1 = Ws[kk][tx * 4 + 1];
      float b2 = Ws[kk][tx * 4 + 2], b3 = Ws[kk][tx * 4 + 3];
      acc[0][0] += a0 * b0; acc[0][1] += a0 * b1; acc[0][2] += a0 * b2; acc[0][3] += a0 * b3;
      acc[1][0] += a1 * b0; acc[1][1] += a1 * b1; acc[1][2] += a1 * b2; acc[1][3] += a1 * b3;
      acc[2][0] += a2 * b0; acc[2][1] += a2 * b1; acc[2][2] += a2 * b2; acc[2][3] += a2 * b3;
      acc[3][0] += a3 * b0; acc[3][1] += a3 * b1; acc[3][2] += a3 * b2; acc[3][3] += a3 * b3;
    }
    __syncthreads();
  }
#pragma unroll
  for (int i = 0; i < 4; i++) {
    int p = p0 + ty * 4 + i;
#pragma unroll
    for (int j = 0; j < 4; j++) {
      int n = n0 + tx * 4 + j;
      out[((size_t)(b * HW + p)) * N + n] = acc[i][j] + bias[n];
    }
  }
}

// ------------- implicit-GEMM 3x3 conv, channel-last, zero pad 1 -------------
// T: (B,128,128,256), Wt: (256, 9*256) with k = tap*256+c, out: (B,HW,256)
__global__ __launch_bounds__(256) void conv3x3_gemm(
    const float* __restrict__ T, const float* __restrict__ Wt,
    const float* __restrict__ bias, float* __restrict__ out) {
  __shared__ float As[16][65];
  __shared__ float Ws[16][65];
  const int tid = threadIdx.x;
  const int tx = tid & 15, ty = tid >> 4;
  const int m0 = blockIdx.y * 64, n0 = blockIdx.x * 64;
  const int b = m0 >> 14;
  const int p0 = m0 & 16383;
  const int y = p0 >> 7;
  const int x0 = p0 & 127;
  float acc[4][4] = {{0.f}};
  for (int kc = 0; kc < 144; kc++) {
    int k0 = kc * 16;
    int tap = k0 >> 8;
    int cbase = k0 & 255;
    int dy = tap / 3 - 1, dx = tap % 3 - 1;
    int yy = y + dy;
#pragma unroll
    for (int i = 0; i < 4; i++) {
      int idx = tid + i * 256;
      int r = idx >> 4, kk = idx & 15;
      int xx = x0 + r + dx;
      float v = 0.f;
      if (yy >= 0 && yy < 128 && xx >= 0 && xx < 128)
        v = T[((size_t)(b * 16384 + yy * 128 + xx)) * 256 + cbase + kk];
      As[kk][r] = v;
      Ws[kk][r] = Wt[(size_t)(n0 + r) * 2304 + k0 + kk];
    }
    __syncthreads();
#pragma unroll
    for (int kk = 0; kk < 16; kk++) {
      float a0 = As[kk][ty * 4 + 0], a1 = As[kk][ty * 4 + 1];
      float a2 = As[kk][ty * 4 + 2], a3 = As[kk][ty * 4 + 3];
      float b0 = Ws[kk][tx * 4 + 0], b1 = Ws[kk][tx * 4 + 1];
      float b2 = Ws[kk][tx * 4 + 2], b3 = Ws[kk][tx * 4 + 3];
      acc[0][0] += a0 * b0; acc[0][1] += a0 * b1; acc[0][2] += a0 * b2; acc[0][3] += a0 * b3;
      acc[1][0] += a1 * b0; acc[1][1] += a1 * b1; acc[1][2] += a1 * b2; acc[1][3] += a1 * b3;
      acc[2][0] += a2 * b0; acc[2][1] += a2 * b1; acc[2][2] += a2 * b2; acc[2][3] += a2 * b3;
      acc[3][0] += a3 * b0; acc[3][1] += a3 * b1; acc[3][2] += a3 * b2; acc[3][3] += a3 * b3;
    }
    __syncthreads();
  }
#pragma unroll
  for (int i = 0; i < 4; i++) {
    int p = p0 + ty * 4 + i;
#pragma unroll
    for (int j = 0; j < 4; j++) {
      int n = n0 + tx * 4 + j;
      out[((size_t)(b * 16384 + p)) * 256 + n] = acc[i][j] + bias[n];
    }
  }
}

// ---------------- deformable sampling + fused softmax ----------------
__global__ __launch_bounds__(256) void msda_sample(
    const float* __restrict__ value, const float* __restrict__ off,
    const float* __restrict__ awl, float* __restrict__ attn) {
  int gid = blockIdx.x * 8 + (threadIdx.x >> 5);
  int lane = threadIdx.x & 31;
  int h = gid & 7;
  int bn = gid >> 3;
  int n = bn % Ntok;
  int b = bn / Ntok;

  int li0 = (n < 4096) ? 0 : ((n < 5120) ? 1 : 2);
  int start0 = (li0 == 0) ? 0 : ((li0 == 1) ? 4096 : 5120);
  int shift = 6 - li0;
  int Wn = 1 << shift;
  int sp = n - start0;
  int iy = sp >> shift;
  int ix = sp & (Wn - 1);
  float refx = (ix + 0.5f) / (float)Wn;
  float refy = (iy + 0.5f) / (float)Wn;

  // softmax over 12 attention logits (all lanes redundantly)
  const float* ap = awl + (size_t)bn * 96 + h * 12;
  float lg[12];
  float mx = -1e30f;
#pragma unroll
  for (int j = 0; j < 12; j++) { lg[j] = ap[j]; mx = fmaxf(mx, lg[j]); }
  float ssum = 0.f;
#pragma unroll
  for (int j = 0; j < 12; j++) { lg[j] = expf(lg[j] - mx); ssum += lg[j]; }
  float inv = 1.f / ssum;

  const float* op = off + (size_t)bn * 192 + h * 24;
  float acc = 0.f;
#pragma unroll
  for (int li = 0; li < 3; li++) {
    int HWl = 64 >> li;
    int st = (li == 0) ? 0 : ((li == 1) ? 4096 : 5120);
    const float* vb = value + ((size_t)(b * Ntok + st) * 8 + h) * 32 + lane;
#pragma unroll
    for (int p = 0; p < 4; p++) {
      float ox = op[(li * 4 + p) * 2 + 0];
      float oy = op[(li * 4 + p) * 2 + 1];
      float lx = refx + ox / (float)HWl;
      float ly = refy + oy / (float)HWl;
      float fx = lx * (float)HWl - 0.5f;
      float fy = ly * (float)HWl - 0.5f;
      float x0f = floorf(fx), y0f = floorf(fy);
      float wx = fx - x0f, wy = fy - y0f;
      int ix0 = (int)x0f, iy0 = (int)y0f;
      float w = lg[li * 4 + p] * inv;
      float w00 = w * (1.f - wx) * (1.f - wy);
      float w01 = w * wx * (1.f - wy);
      float w10 = w * (1.f - wx) * wy;
      float w11 = w * wx * wy;
      if (ix0 >= 0 && ix0 < HWl && iy0 >= 0 && iy0 < HWl)
        acc += w00 * vb[(size_t)(iy0 * HWl + ix0) * 256];
      if (ix0 + 1 >= 0 && ix0 + 1 < HWl && iy0 >= 0 && iy0 < HWl)
        acc += w01 * vb[(size_t)(iy0 * HWl + ix0 + 1) * 256];
      if (ix0 >= 0 && ix0 < HWl && iy0 + 1 >= 0 && iy0 + 1 < HWl)
        acc += w10 * vb[(size_t)((iy0 + 1) * HWl + ix0) * 256];
      if (ix0 + 1 >= 0 && ix0 + 1 < HWl && iy0 + 1 >= 0 && iy0 + 1 < HWl)
        acc += w11 * vb[(size_t)((iy0 + 1) * HWl + ix0 + 1) * 256];
    }
  }
  attn[((size_t)bn * 8 + h) * 32 + lane] = acc;
}

// ---------------- residual add + LayerNorm (in place into x) ----------------
__global__ __launch_bounds__(256) void ln_residual(
    float* __restrict__ x, const float* __restrict__ r,
    const float* __restrict__ g, const float* __restrict__ bta) {
  int row = blockIdx.x;
  int c = threadIdx.x;
  float v = x[(size_t)row * 256 + c] + r[(size_t)row * 256 + c];
  __shared__ float red[256];
  red[c] = v;
  __syncthreads();
  for (int s = 128; s > 0; s >>= 1) {
    if (c < s) red[c] += red[c + s];
    __syncthreads();
  }
  float mu = red[0] * (1.f / 256.f);
  __syncthreads();
  float d = v - mu;
  red[c] = d * d;
  __syncthreads();
  for (int s = 128; s > 0; s >>= 1) {
    if (c < s) red[c] += red[c + s];
    __syncthreads();
  }
  float var = red[0] * (1.f / 256.f);
  x[(size_t)row * 256 + c] = d * rsqrtf(var + EPSf) * g[c] + bta[c];
}

// ---------------- bilinear 64->128 upsample of level-0 tokens, += into t ----------------
__global__ __launch_bounds__(256) void upsample_add(
    const float* __restrict__ xrows, float* __restrict__ t) {
  int bp = blockIdx.x;  // b*16384 + p
  int c = threadIdx.x;
  int b = bp >> 14;
  int p = bp & 16383;
  int Y = p >> 7, X = p & 127;
  float yc = Y * 0.5f - 0.25f;
  float y0f = floorf(yc);
  float wy = yc - y0f;
  int y0 = (int)y0f, y1 = y0 + 1;
  int y0c = min(max(y0, 0), 63), y1c = min(max(y1, 0), 63);
  float xc = X * 0.5f - 0.25f;
  float x0f = floorf(xc);
  float wx = xc - x0f;
  int xq0 = (int)x0f, xq1 = xq0 + 1;
  int x0c = min(max(xq0, 0), 63), x1c = min(max(xq1, 0), 63);
  const float* base = xrows + (size_t)b * Ntok * 256;
  float v00 = base[(size_t)(y0c * 64 + x0c) * 256 + c];
  float v01 = base[(size_t)(y0c * 64 + x1c) * 256 + c];
  float v10 = base[(size_t)(y1c * 64 + x0c) * 256 + c];
  float v11 = base[(size_t)(y1c * 64 + x1c) * 256 + c];
  float v = (1.f - wy) * ((1.f - wx) * v00 + wx * v01) +
            wy * ((1.f - wx) * v10 + wx * v11);
  t[(size_t)bp * 256 + c] += v;
}

// ---------------- token rows -> NCHW output (tiled transpose) ----------------
__global__ void rows_to_nchw(const float* __restrict__ xrows,
                             float* __restrict__ out, int start, int size) {
  __shared__ float tile[32][33];
  int p0 = blockIdx.x * 32, c0 = blockIdx.y * 32, b = blockIdx.z;
  int tx = threadIdx.x, tyy = threadIdx.y;
  for (int i = tyy; i < 32; i += 8)
    tile[i][tx] = xrows[((size_t)(b * Ntok + start + p0 + i)) * 256 + c0 + tx];
  __syncthreads();
  for (int i = tyy; i < 32; i += 8)
    out[((size_t)(b * 256 + c0 + i)) * size + p0 + tx] = tile[tx][i];
}

// ---------------- conv weight repack (O,C,3,3) -> (O, tap*256+c) ----------------
__global__ void wt_transpose(const float* __restrict__ w,
                             float* __restrict__ wt) {
  for (int i = blockIdx.x * blockDim.x + threadIdx.x; i < 256 * 2304;
       i += gridDim.x * blockDim.x) {
    int o = i / 2304;
    int r = i % 2304;
    int tap = r >> 8;
    int c = r & 255;
    wt[i] = w[((size_t)(o * 256 + c)) * 9 + tap];
  }
}

// ---------------- GroupNorm partial sums ----------------
__global__ __launch_bounds__(256) void gn_partial(
    const float* __restrict__ s, float* __restrict__ part) {
  int blk = blockIdx.x;  // ((b*32+g)*16 + part)
  int pr = blk & 15;
  int bg = blk >> 4;
  int g = bg & 31;
  int b = bg >> 5;
  int tid = threadIdx.x;
  float sum = 0.f, sq = 0.f;
  for (int e = pr * 8192 + tid; e < (pr + 1) * 8192; e += 256) {
    int p = e >> 3, cc = e & 7;
    float v = s[((size_t)(b * 16384 + p)) * 256 + g * 8 + cc];
    sum += v;
    sq += v * v;
  }
  __shared__ float rs[256], rq[256];
  rs[tid] = sum;
  rq[tid] = sq;
  __syncthreads();
  for (int st = 128; st > 0; st >>= 1) {
    if (tid < st) { rs[tid] += rs[tid + st]; rq[tid] += rq[tid + st]; }
    __syncthreads();
  }
  if (tid == 0) {
    part[(size_t)blk * 2 + 0] = rs[0];
    part[(size_t)blk * 2 + 1] = rq[0];
  }
}

__global__ void gn_final(const float* __restrict__ part,
                         float* __restrict__ stats) {
  int tid = threadIdx.x;
  if (tid < 64) {
    float s = 0.f, q = 0.f;
    for (int j = 0; j < 16; j++) {
      s += part[(size_t)(tid * 16 + j) * 2 + 0];
      q += part[(size_t)(tid * 16 + j) * 2 + 1];
    }
    float mu = s * (1.f / 131072.f);
    float var = q * (1.f / 131072.f) - mu * mu;
    stats[tid * 2 + 0] = mu;
    stats[tid * 2 + 1] = rsqrtf(var + EPSf);
  }
}

// ---------------- GN apply + GELU + transpose to NCHW ----------------
__global__ void gn_apply(const float* __restrict__ s,
                         const float* __restrict__ stats,
                         const float* __restrict__ gg,
                         const float* __restrict__ gb,
                         float* __restrict__ out) {
  __shared__ float tile[32][33];
  int p0 = blockIdx.x * 32, c0 = blockIdx.y * 32, b = blockIdx.z;
  int tx = threadIdx.x, tyy = threadIdx.y;
  int c = c0 + tx;
  float mu = stats[(b * 32 + (c >> 3)) * 2 + 0];
  float rstd = stats[(b * 32 + (c >> 3)) * 2 + 1];
  float gw = gg[c], bw = gb[c];
  for (int i = tyy; i < 32; i += 8) {
    float v = s[((size_t)(b * 16384 + p0 + i)) * 256 + c];
    v = (v - mu) * rstd * gw + bw;
    v = 0.5f * v * (1.f + erff(v * 0.70710678118654752f));
    tile[i][tx] = v;
  }
  __syncthreads();
  for (int i = tyy; i < 32; i += 8)
    out[((size_t)(b * 256 + c0 + i)) * 16384 + p0 + tx] = tile[tx][i];
}

// ---------------- launcher ----------------
extern "C" void kernel_launch(void* const* d_in, const int* in_sizes, int n_in,
                              void* d_out, int out_size, void* d_ws,
                              size_t ws_size, hipStream_t stream) {
  (void)in_sizes; (void)n_in; (void)out_size; (void)ws_size;
  const float* res2  = (const float*)d_in[0];
  const float* res3  = (const float*)d_in[1];
  const float* res4  = (const float*)d_in[2];
  const float* res5  = (const float*)d_in[3];
  const float* lemb  = (const float*)d_in[4];
  const float* off_W = (const float*)d_in[5];
  const float* off_b = (const float*)d_in[6];
  const float* aw_W  = (const float*)d_in[7];
  const float* aw_b  = (const float*)d_in[8];
  const float* val_W = (const float*)d_in[9];
  const float* val_b = (const float*)d_in[10];
  const float* out_W = (const float*)d_in[11];
  const float* out_b = (const float*)d_in[12];
  const float* ln1_g = (const float*)d_in[13];
  const float* ln1_b = (const float*)d_in[14];
  const float* fc1_W = (const float*)d_in[15];
  const float* fc1_b = (const float*)d_in[16];
  const float* fc2_W = (const float*)d_in[17];
  const float* fc2_b = (const float*)d_in[18];
  const float* ln2_g = (const float*)d_in[19];
  const float* ln2_b = (const float*)d_in[20];
  const float* lat_W = (const float*)d_in[21];
  const float* lat_b = (const float*)d_in[22];
  const float* sm_W  = (const float*)d_in[23];
  const float* sm_b  = (const float*)d_in[24];
  const float* gn_g  = (const float*)d_in[25];
  const float* gn_b  = (const float*)d_in[26];

  float* ws = (float*)d_ws;
  const size_t BNC = (size_t)Bn * Ntok * Cc;  // 2752512
  float* x      = ws;
  float* pe     = x + BNC;                    // 1376256
  float* q      = pe + (size_t)Ntok * Cc;
  float* value  = q + BNC;
  float* offb   = value + BNC;                // 2064384
  float* awl    = offb + (size_t)Bn * Ntok * 192;
  float* attn   = awl + (size_t)Bn * Ntok * 96;
  float* tmp    = attn + BNC;
  float* hbuf   = tmp + BNC;                  // 11010048 (also conv-input alias)
  float* tbuf   = hbuf;                       // conv input (B,HW,256), used after layers
  float* wtbuf  = hbuf + (size_t)Bn * Ntok * Ffn;
  float* gnpart = wtbuf + 256 * 2304;
  float* gnstat = gnpart + 2048;
  float* sbuf   = x;  // conv output aliases x..value region (dead by then)

  float* out_s  = (float*)d_out;
  float* out_o3 = out_s + (size_t)Bn * Cc * HW2;
  float* out_o4 = out_o3 + (size_t)Bn * Cc * 4096;
  float* out_o5 = out_o4 + (size_t)Bn * Cc * 1024;

  const int M = Bn * Ntok;  // 10752

  pe_kernel<<<1024, 256, 0, stream>>>(pe);
  flatten_kernel<<<1024, 256, 0, stream>>>(res3, res4, res5, lemb, x);

  for (int l = 0; l < 6; l++) {
    addpe_kernel<<<1024, 256, 0, stream>>>(x, pe, q);
    gemm_bias<<<dim3(4, 168), 256, 0, stream>>>(
        x, val_W + (size_t)l * 65536, val_b + l * 256, value, M, 256, 256, 0);
    gemm_bias<<<dim3(3, 168), 256, 0, stream>>>(
        q, off_W + (size_t)l * 49152, off_b + l * 192, offb, M, 192, 256, 0);
    gemm_bias<<<dim3(2, 168), 256, 0, stream>>>(
        q, aw_W + (size_t)l * 24576, aw_b + l * 96, awl, M, 96, 256, 0);
    msda_sample<<<10752, 256, 0, stream>>>(value, offb, awl, attn);
    gemm_bias<<<dim3(4, 168), 256, 0, stream>>>(
        attn, out_W + (size_t)l * 65536, out_b + l * 256, tmp, M, 256, 256, 0);
    ln_residual<<<M, 256, 0, stream>>>(x, tmp, ln1_g + l * 256, ln1_b + l * 256);
    gemm_bias<<<dim3(16, 168), 256, 0, stream>>>(
        x, fc1_W + (size_t)l * 262144, fc1_b + l * 1024, hbuf, M, 1024, 256, 1);
    gemm_bias<<<dim3(4, 168), 256, 0, stream>>>(
        hbuf, fc2_W + (size_t)l * 262144, fc2_b + l * 256, tmp, M, 256, 1024, 0);
    ln_residual<<<M, 256, 0, stream>>>(x, tmp, ln2_g + l * 256, ln2_b + l * 256);
  }

  // token outputs (read x) — must precede sbuf (aliases x) writes
  rows_to_nchw<<<dim3(128, 8, 2), dim3(32, 8), 0, stream>>>(x, out_o3, 0, 4096);
  rows_to_nchw<<<dim3(32, 8, 2), dim3(32, 8), 0, stream>>>(x, out_o4, 4096, 1024);
  rows_to_nchw<<<dim3(8, 8, 2), dim3(32, 8), 0, stream>>>(x, out_o5, 5120, 256);

  // FPN tail
  gemm_tn_bias<<<dim3(4, 512), 256, 0, stream>>>(res2, lat_W, lat_b, tbuf,
                                                 HW2, 256, 256);
  upsample_add<<<32768, 256, 0, stream>>>(x, tbuf);
  wt_transpose<<<1024, 256, 0, stream>>>(sm_W, wtbuf);
  conv3x3_gemm<<<dim3(4, 512), 256, 0, stream>>>(tbuf, wtbuf, sm_b, sbuf);
  gn_partial<<<1024, 256, 0, stream>>>(sbuf, gnpart);
  gn_final<<<1, 64, 0, stream>>>(gnpart, gnstat);
  gn_apply<<<dim3(512, 8, 2), dim3(32, 8), 0, stream>>>(sbuf, gnstat, gn_g,
                                                        gn_b, out_s);
}

// Round 2
// 1775.811 us; speedup vs baseline: 2.7724x; 2.7724x over previous
//
#include <hip/hip_runtime.h>

// ---------------- constants ----------------
namespace {
constexpr int Bn   = 2;
constexpr int Cc   = 256;
constexpr int Ntok = 5376;      // 4096 + 1024 + 256
constexpr int Ffn  = 1024;
constexpr int HW2  = 128 * 128; // res2 spatial
constexpr float EPSf = 1e-5f;
}

typedef __attribute__((ext_vector_type(8))) short bf16x8;
typedef __attribute__((ext_vector_type(4))) float f32x4;

__device__ inline unsigned short f2bf(float x) {
  unsigned u = __float_as_uint(x);
  return (unsigned short)((u + 0x7fffu + ((u >> 16) & 1u)) >> 16);
}

// write one 16B chunk (8 bf16) to LDS with XOR-swizzled granule
__device__ inline void store_chunk(unsigned short* lds, int row, int g,
                                   const float* v8) {
  int sg = g ^ (row & 7);
  unsigned short tmp[8];
#pragma unroll
  for (int j = 0; j < 8; j++) tmp[j] = f2bf(v8[j]);
  *reinterpret_cast<uint4*>(&lds[row * 64 + sg * 8]) =
      *reinterpret_cast<const uint4*>(tmp);
}

// ---------------- positional encoding ----------------
__global__ void pe_kernel(float* __restrict__ pe) {
  for (int i = blockIdx.x * blockDim.x + threadIdx.x; i < Ntok * Cc;
       i += gridDim.x * blockDim.x) {
    int c = i & 255;
    int p = i >> 8;
    int li = (p < 4096) ? 0 : ((p < 5120) ? 1 : 2);
    int start = (li == 0) ? 0 : ((li == 1) ? 4096 : 5120);
    int W = 64 >> li;
    int sp = p - start;
    int shift = 6 - li;
    int iy = sp >> shift;
    int ix = sp & (W - 1);
    int j = c & 63;
    int sel = c >> 6;
    float div = expf(-(float)j * (9.210340371976184f / 64.f)); // ln(1e4)/64
    float coord = (sel < 2) ? (float)iy : (float)ix;
    float arg = coord * div;
    pe[i] = (sel & 1) ? cosf(arg) : sinf(arg);
  }
}

// ---------------- flatten + level_embed ----------------
__global__ void flatten_kernel(const float* __restrict__ r3,
                               const float* __restrict__ r4,
                               const float* __restrict__ r5,
                               const float* __restrict__ lemb,
                               float* __restrict__ x) {
  for (int i = blockIdx.x * blockDim.x + threadIdx.x; i < Bn * Ntok * Cc;
       i += gridDim.x * blockDim.x) {
    int c = i & 255;
    int rest = i >> 8;
    int p = rest % Ntok;
    int b = rest / Ntok;
    int li = (p < 4096) ? 0 : ((p < 5120) ? 1 : 2);
    int start = (li == 0) ? 0 : ((li == 1) ? 4096 : 5120);
    int size = (li == 0) ? 4096 : ((li == 1) ? 1024 : 256);
    const float* f = (li == 0) ? r3 : ((li == 1) ? r4 : r5);
    int sp = p - start;
    x[i] = f[((size_t)(b * Cc + c)) * size + sp] + lemb[li * Cc + c];
  }
}

// ---------------- q = x + pe ----------------
__global__ void addpe_kernel(const float* __restrict__ x,
                             const float* __restrict__ pe,
                             float* __restrict__ q) {
  const int NPC = Ntok * Cc;
  for (int i = blockIdx.x * blockDim.x + threadIdx.x; i < Bn * NPC;
       i += gridDim.x * blockDim.x) {
    int pc = (i >= NPC) ? i - NPC : i;
    q[i] = x[i] + pe[pc];
  }
}

// =================================================================
// MFMA GEMM family: out(M,N) = A(M,K) @ W(N,K)^T + bias, bf16 MFMA,
// fp32 in/out. BM=64, BN=128, BK=64. 256 threads = 4 waves (2x2),
// wave tile 32x64 via 16x16x32 mfma. LDS XOR-swizzle (T2).
// =================================================================
template <int ACT>
__global__ __launch_bounds__(256) void gemm_mfma(
    const float* __restrict__ A, const float* __restrict__ W,
    const float* __restrict__ bias, float* __restrict__ out,
    int M, int N, int K) {
  __shared__ unsigned short As[64 * 64];
  __shared__ unsigned short Ws[128 * 64];
  const int tid = threadIdx.x;
  const int m0 = blockIdx.y * 64, n0 = blockIdx.x * 128;
  const int wid = tid >> 6, lane = tid & 63;
  const int wm = wid >> 1, wn = wid & 1;
  const int lr = lane & 15, lh = lane >> 4;
  f32x4 acc[2][4];
#pragma unroll
  for (int i = 0; i < 2; i++)
#pragma unroll
    for (int j = 0; j < 4; j++) acc[i][j] = f32x4{0.f, 0.f, 0.f, 0.f};

  for (int k0 = 0; k0 < K; k0 += 64) {
    // stage A: 64 rows x 8 granules = 512 chunks, 2 per thread
#pragma unroll
    for (int i = 0; i < 2; i++) {
      int c = tid + i * 256;
      int row = c >> 3, g = c & 7;
      const float4* src =
          reinterpret_cast<const float4*>(A + (size_t)(m0 + row) * K + k0 + g * 8);
      float4 v0 = src[0], v1 = src[1];
      float v8[8] = {v0.x, v0.y, v0.z, v0.w, v1.x, v1.y, v1.z, v1.w};
      store_chunk(As, row, g, v8);
    }
    // stage W: 128 rows x 8 granules = 1024 chunks, 4 per thread
#pragma unroll
    for (int i = 0; i < 4; i++) {
      int c = tid + i * 256;
      int row = c >> 3, g = c & 7;
      int n = n0 + row;
      float v8[8] = {0.f, 0.f, 0.f, 0.f, 0.f, 0.f, 0.f, 0.f};
      if (n < N) {
        const float4* src =
            reinterpret_cast<const float4*>(W + (size_t)n * K + k0 + g * 8);
        float4 v0 = src[0], v1 = src[1];
        v8[0] = v0.x; v8[1] = v0.y; v8[2] = v0.z; v8[3] = v0.w;
        v8[4] = v1.x; v8[5] = v1.y; v8[6] = v1.z; v8[7] = v1.w;
      }
      store_chunk(Ws, row, g, v8);
    }
    __syncthreads();
    bf16x8 af[2][2], bfr[4][2];
#pragma unroll
    for (int mi = 0; mi < 2; mi++) {
      int r = wm * 32 + mi * 16 + lr;
#pragma unroll
      for (int s = 0; s < 2; s++) {
        int g = s * 4 + lh;
        af[mi][s] =
            *reinterpret_cast<const bf16x8*>(&As[r * 64 + (g ^ (r & 7)) * 8]);
      }
    }
#pragma unroll
    for (int nj = 0; nj < 4; nj++) {
      int r = wn * 64 + nj * 16 + lr;
#pragma unroll
      for (int s = 0; s < 2; s++) {
        int g = s * 4 + lh;
        bfr[nj][s] =
            *reinterpret_cast<const bf16x8*>(&Ws[r * 64 + (g ^ (r & 7)) * 8]);
      }
    }
#pragma unroll
    for (int mi = 0; mi < 2; mi++)
#pragma unroll
      for (int nj = 0; nj < 4; nj++) {
        acc[mi][nj] = __builtin_amdgcn_mfma_f32_16x16x32_bf16(
            af[mi][0], bfr[nj][0], acc[mi][nj], 0, 0, 0);
        acc[mi][nj] = __builtin_amdgcn_mfma_f32_16x16x32_bf16(
            af[mi][1], bfr[nj][1], acc[mi][nj], 0, 0, 0);
      }
    __syncthreads();
  }
  // epilogue: D mapping col=lane&15, row=(lane>>4)*4+reg
#pragma unroll
  for (int mi = 0; mi < 2; mi++) {
    int row = m0 + wm * 32 + mi * 16 + lh * 4;
#pragma unroll
    for (int nj = 0; nj < 4; nj++) {
      int col = n0 + wn * 64 + nj * 16 + lr;
      if (col >= N) continue;
      float b = bias[col];
#pragma unroll
      for (int r = 0; r < 4; r++) {
        float v = acc[mi][nj][r] + b;
        if (ACT) v = fmaxf(v, 0.f);
        out[(size_t)(row + r) * N + col] = v;
      }
    }
  }
}

// ------------- implicit-GEMM 3x3 conv, channel-last, zero pad 1 -------------
// T: (B,128,128,256) fp32, Wt: (256, 9*256), out: (B,HW,256) fp32
__global__ __launch_bounds__(256) void conv3x3_mfma(
    const float* __restrict__ T, const float* __restrict__ Wt,
    const float* __restrict__ bias, float* __restrict__ out) {
  __shared__ unsigned short As[64 * 64];
  __shared__ unsigned short Ws[128 * 64];
  const int tid = threadIdx.x;
  const int m0 = blockIdx.y * 64, n0 = blockIdx.x * 128;
  const int b = m0 >> 14;
  const int p0 = m0 & 16383;
  const int y = p0 >> 7;
  const int x0 = p0 & 127;  // 0 or 64
  const int wid = tid >> 6, lane = tid & 63;
  const int wm = wid >> 1, wn = wid & 1;
  const int lr = lane & 15, lh = lane >> 4;
  f32x4 acc[2][4];
#pragma unroll
  for (int i = 0; i < 2; i++)
#pragma unroll
    for (int j = 0; j < 4; j++) acc[i][j] = f32x4{0.f, 0.f, 0.f, 0.f};

  for (int k0 = 0; k0 < 2304; k0 += 64) {
    int tap = k0 >> 8;
    int cb = k0 & 255;
    int dy = tap / 3 - 1, dx = tap % 3 - 1;
    int yy = y + dy;
#pragma unroll
    for (int i = 0; i < 2; i++) {
      int c = tid + i * 256;
      int row = c >> 3, g = c & 7;
      int xx = x0 + row + dx;
      float v8[8] = {0.f, 0.f, 0.f, 0.f, 0.f, 0.f, 0.f, 0.f};
      if (yy >= 0 && yy < 128 && xx >= 0 && xx < 128) {
        const float4* src = reinterpret_cast<const float4*>(
            T + ((size_t)(b * 16384 + yy * 128 + xx)) * 256 + cb + g * 8);
        float4 v0 = src[0], v1 = src[1];
        v8[0] = v0.x; v8[1] = v0.y; v8[2] = v0.z; v8[3] = v0.w;
        v8[4] = v1.x; v8[5] = v1.y; v8[6] = v1.z; v8[7] = v1.w;
      }
      store_chunk(As, row, g, v8);
    }
#pragma unroll
    for (int i = 0; i < 4; i++) {
      int c = tid + i * 256;
      int row = c >> 3, g = c & 7;
      const float4* src = reinterpret_cast<const float4*>(
          Wt + (size_t)(n0 + row) * 2304 + k0 + g * 8);
      float4 v0 = src[0], v1 = src[1];
      float v8[8] = {v0.x, v0.y, v0.z, v0.w, v1.x, v1.y, v1.z, v1.w};
      store_chunk(Ws, row, g, v8);
    }
    __syncthreads();
    bf16x8 af[2][2], bfr[4][2];
#pragma unroll
    for (int mi = 0; mi < 2; mi++) {
      int r = wm * 32 + mi * 16 + lr;
#pragma unroll
      for (int s = 0; s < 2; s++) {
        int g = s * 4 + lh;
        af[mi][s] =
            *reinterpret_cast<const bf16x8*>(&As[r * 64 + (g ^ (r & 7)) * 8]);
      }
    }
#pragma unroll
    for (int nj = 0; nj < 4; nj++) {
      int r = wn * 64 + nj * 16 + lr;
#pragma unroll
      for (int s = 0; s < 2; s++) {
        int g = s * 4 + lh;
        bfr[nj][s] =
            *reinterpret_cast<const bf16x8*>(&Ws[r * 64 + (g ^ (r & 7)) * 8]);
      }
    }
#pragma unroll
    for (int mi = 0; mi < 2; mi++)
#pragma unroll
      for (int nj = 0; nj < 4; nj++) {
        acc[mi][nj] = __builtin_amdgcn_mfma_f32_16x16x32_bf16(
            af[mi][0], bfr[nj][0], acc[mi][nj], 0, 0, 0);
        acc[mi][nj] = __builtin_amdgcn_mfma_f32_16x16x32_bf16(
            af[mi][1], bfr[nj][1], acc[mi][nj], 0, 0, 0);
      }
    __syncthreads();
  }
#pragma unroll
  for (int mi = 0; mi < 2; mi++) {
    int row = m0 + wm * 32 + mi * 16 + lh * 4;
#pragma unroll
    for (int nj = 0; nj < 4; nj++) {
      int col = n0 + wn * 64 + nj * 16 + lr;
      float b = bias[col];
#pragma unroll
      for (int r = 0; r < 4; r++)
        out[(size_t)(row + r) * 256 + col] = acc[mi][nj][r] + b;
    }
  }
}

// ------------- TN GEMM (1x1 lateral conv): A=(B,256,HW) NCHW -------------
// out: (B,HW,256) fp32. A-loader reads coalesced along pixels per k-plane.
__global__ __launch_bounds__(256) void gemm_tn_mfma(
    const float* __restrict__ A, const float* __restrict__ W,
    const float* __restrict__ bias, float* __restrict__ out) {
  __shared__ unsigned short As[64 * 64];
  __shared__ unsigned short Ws[128 * 64];
  const int tid = threadIdx.x;
  const int m0 = blockIdx.y * 64, n0 = blockIdx.x * 128;
  const int b = m0 >> 14;
  const int p0 = m0 & 16383;
  const int wid = tid >> 6, lane = tid & 63;
  const int wm = wid >> 1, wn = wid & 1;
  const int lr = lane & 15, lh = lane >> 4;
  f32x4 acc[2][4];
#pragma unroll
  for (int i = 0; i < 2; i++)
#pragma unroll
    for (int j = 0; j < 4; j++) acc[i][j] = f32x4{0.f, 0.f, 0.f, 0.f};

  for (int k0 = 0; k0 < 256; k0 += 64) {
    // A chunks: row = pixel (c&63), g = k-granule (c>>6): coalesced in pixels
#pragma unroll
    for (int i = 0; i < 2; i++) {
      int c = tid + i * 256;
      int row = c & 63, g = c >> 6;
      float v8[8];
#pragma unroll
      for (int j = 0; j < 8; j++)
        v8[j] = A[(size_t)(b * 256 + k0 + g * 8 + j) * 16384 + p0 + row];
      store_chunk(As, row, g, v8);
    }
#pragma unroll
    for (int i = 0; i < 4; i++) {
      int c = tid + i * 256;
      int row = c >> 3, g = c & 7;
      const float4* src =
          reinterpret_cast<const float4*>(W + (size_t)(n0 + row) * 256 + k0 + g * 8);
      float4 v0 = src[0], v1 = src[1];
      float v8[8] = {v0.x, v0.y, v0.z, v0.w, v1.x, v1.y, v1.z, v1.w};
      store_chunk(Ws, row, g, v8);
    }
    __syncthreads();
    bf16x8 af[2][2], bfr[4][2];
#pragma unroll
    for (int mi = 0; mi < 2; mi++) {
      int r = wm * 32 + mi * 16 + lr;
#pragma unroll
      for (int s = 0; s < 2; s++) {
        int g = s * 4 + lh;
        af[mi][s] =
            *reinterpret_cast<const bf16x8*>(&As[r * 64 + (g ^ (r & 7)) * 8]);
      }
    }
#pragma unroll
    for (int nj = 0; nj < 4; nj++) {
      int r = wn * 64 + nj * 16 + lr;
#pragma unroll
      for (int s = 0; s < 2; s++) {
        int g = s * 4 + lh;
        bfr[nj][s] =
            *reinterpret_cast<const bf16x8*>(&Ws[r * 64 + (g ^ (r & 7)) * 8]);
      }
    }
#pragma unroll
    for (int mi = 0; mi < 2; mi++)
#pragma unroll
      for (int nj = 0; nj < 4; nj++) {
        acc[mi][nj] = __builtin_amdgcn_mfma_f32_16x16x32_bf16(
            af[mi][0], bfr[nj][0], acc[mi][nj], 0, 0, 0);
        acc[mi][nj] = __builtin_amdgcn_mfma_f32_16x16x32_bf16(
            af[mi][1], bfr[nj][1], acc[mi][nj], 0, 0, 0);
      }
    __syncthreads();
  }
#pragma unroll
  for (int mi = 0; mi < 2; mi++) {
    int row = m0 + wm * 32 + mi * 16 + lh * 4;
#pragma unroll
    for (int nj = 0; nj < 4; nj++) {
      int col = n0 + wn * 64 + nj * 16 + lr;
      float b = bias[col];
#pragma unroll
      for (int r = 0; r < 4; r++)
        out[(size_t)(row + r) * 256 + col] = acc[mi][nj][r] + b;
    }
  }
}

// ---------------- deformable sampling + fused softmax ----------------
__global__ __launch_bounds__(256) void msda_sample(
    const float* __restrict__ value, const float* __restrict__ off,
    const float* __restrict__ awl, float* __restrict__ attn) {
  int gid = blockIdx.x * 8 + (threadIdx.x >> 5);
  int lane = threadIdx.x & 31;
  int h = gid & 7;
  int bn = gid >> 3;
  int n = bn % Ntok;
  int b = bn / Ntok;

  int li0 = (n < 4096) ? 0 : ((n < 5120) ? 1 : 2);
  int start0 = (li0 == 0) ? 0 : ((li0 == 1) ? 4096 : 5120);
  int shift = 6 - li0;
  int Wn = 1 << shift;
  int sp = n - start0;
  int iy = sp >> shift;
  int ix = sp & (Wn - 1);
  float refx = (ix + 0.5f) / (float)Wn;
  float refy = (iy + 0.5f) / (float)Wn;

  const float* ap = awl + (size_t)bn * 96 + h * 12;
  float lg[12];
  float mx = -1e30f;
#pragma unroll
  for (int j = 0; j < 12; j++) { lg[j] = ap[j]; mx = fmaxf(mx, lg[j]); }
  float ssum = 0.f;
#pragma unroll
  for (int j = 0; j < 12; j++) { lg[j] = expf(lg[j] - mx); ssum += lg[j]; }
  float inv = 1.f / ssum;

  const float* op = off + (size_t)bn * 192 + h * 24;
  float acc = 0.f;
#pragma unroll
  for (int li = 0; li < 3; li++) {
    int HWl = 64 >> li;
    int st = (li == 0) ? 0 : ((li == 1) ? 4096 : 5120);
    const float* vb = value + ((size_t)(b * Ntok + st) * 8 + h) * 32 + lane;
#pragma unroll
    for (int p = 0; p < 4; p++) {
      float ox = op[(li * 4 + p) * 2 + 0];
      float oy = op[(li * 4 + p) * 2 + 1];
      float lx = refx + ox / (float)HWl;
      float ly = refy + oy / (float)HWl;
      float fx = lx * (float)HWl - 0.5f;
      float fy = ly * (float)HWl - 0.5f;
      float x0f = floorf(fx), y0f = floorf(fy);
      float wx = fx - x0f, wy = fy - y0f;
      int ix0 = (int)x0f, iy0 = (int)y0f;
      float w = lg[li * 4 + p] * inv;
      float w00 = w * (1.f - wx) * (1.f - wy);
      float w01 = w * wx * (1.f - wy);
      float w10 = w * (1.f - wx) * wy;
      float w11 = w * wx * wy;
      if (ix0 >= 0 && ix0 < HWl && iy0 >= 0 && iy0 < HWl)
        acc += w00 * vb[(size_t)(iy0 * HWl + ix0) * 256];
      if (ix0 + 1 >= 0 && ix0 + 1 < HWl && iy0 >= 0 && iy0 < HWl)
        acc += w01 * vb[(size_t)(iy0 * HWl + ix0 + 1) * 256];
      if (ix0 >= 0 && ix0 < HWl && iy0 + 1 >= 0 && iy0 + 1 < HWl)
        acc += w10 * vb[(size_t)((iy0 + 1) * HWl + ix0) * 256];
      if (ix0 + 1 >= 0 && ix0 + 1 < HWl && iy0 + 1 >= 0 && iy0 + 1 < HWl)
        acc += w11 * vb[(size_t)((iy0 + 1) * HWl + ix0 + 1) * 256];
    }
  }
  attn[((size_t)bn * 8 + h) * 32 + lane] = acc;
}

// ---------------- residual add + LayerNorm (in place into x) ----------------
__global__ __launch_bounds__(256) void ln_residual(
    float* __restrict__ x, const float* __restrict__ r,
    const float* __restrict__ g, const float* __restrict__ bta) {
  int row = blockIdx.x;
  int c = threadIdx.x;
  float v = x[(size_t)row * 256 + c] + r[(size_t)row * 256 + c];
  __shared__ float red[256];
  red[c] = v;
  __syncthreads();
  for (int s = 128; s > 0; s >>= 1) {
    if (c < s) red[c] += red[c + s];
    __syncthreads();
  }
  float mu = red[0] * (1.f / 256.f);
  __syncthreads();
  float d = v - mu;
  red[c] = d * d;
  __syncthreads();
  for (int s = 128; s > 0; s >>= 1) {
    if (c < s) red[c] += red[c + s];
    __syncthreads();
  }
  float var = red[0] * (1.f / 256.f);
  x[(size_t)row * 256 + c] = d * rsqrtf(var + EPSf) * g[c] + bta[c];
}

// ---------------- bilinear 64->128 upsample of level-0 tokens, += into t ----------------
__global__ __launch_bounds__(256) void upsample_add(
    const float* __restrict__ xrows, float* __restrict__ t) {
  int bp = blockIdx.x;  // b*16384 + p
  int c = threadIdx.x;
  int b = bp >> 14;
  int p = bp & 16383;
  int Y = p >> 7, X = p & 127;
  float yc = Y * 0.5f - 0.25f;
  float y0f = floorf(yc);
  float wy = yc - y0f;
  int y0 = (int)y0f, y1 = y0 + 1;
  int y0c = min(max(y0, 0), 63), y1c = min(max(y1, 0), 63);
  float xc = X * 0.5f - 0.25f;
  float x0f = floorf(xc);
  float wx = xc - x0f;
  int xq0 = (int)x0f, xq1 = xq0 + 1;
  int x0c = min(max(xq0, 0), 63), x1c = min(max(xq1, 0), 63);
  const float* base = xrows + (size_t)b * Ntok * 256;
  float v00 = base[(size_t)(y0c * 64 + x0c) * 256 + c];
  float v01 = base[(size_t)(y0c * 64 + x1c) * 256 + c];
  float v10 = base[(size_t)(y1c * 64 + x0c) * 256 + c];
  float v11 = base[(size_t)(y1c * 64 + x1c) * 256 + c];
  float v = (1.f - wy) * ((1.f - wx) * v00 + wx * v01) +
            wy * ((1.f - wx) * v10 + wx * v11);
  t[(size_t)bp * 256 + c] += v;
}

// ---------------- token rows -> NCHW output (tiled transpose) ----------------
__global__ void rows_to_nchw(const float* __restrict__ xrows,
                             float* __restrict__ out, int start, int size) {
  __shared__ float tile[32][33];
  int p0 = blockIdx.x * 32, c0 = blockIdx.y * 32, b = blockIdx.z;
  int tx = threadIdx.x, tyy = threadIdx.y;
  for (int i = tyy; i < 32; i += 8)
    tile[i][tx] = xrows[((size_t)(b * Ntok + start + p0 + i)) * 256 + c0 + tx];
  __syncthreads();
  for (int i = tyy; i < 32; i += 8)
    out[((size_t)(b * 256 + c0 + i)) * size + p0 + tx] = tile[tx][i];
}

// ---------------- conv weight repack (O,C,3,3) -> (O, tap*256+c) ----------------
__global__ void wt_transpose(const float* __restrict__ w,
                             float* __restrict__ wt) {
  for (int i = blockIdx.x * blockDim.x + threadIdx.x; i < 256 * 2304;
       i += gridDim.x * blockDim.x) {
    int o = i / 2304;
    int r = i % 2304;
    int tap = r >> 8;
    int c = r & 255;
    wt[i] = w[((size_t)(o * 256 + c)) * 9 + tap];
  }
}

// ---------------- GroupNorm partial sums ----------------
__global__ __launch_bounds__(256) void gn_partial(
    const float* __restrict__ s, float* __restrict__ part) {
  int blk = blockIdx.x;  // ((b*32+g)*16 + part)
  int pr = blk & 15;
  int bg = blk >> 4;
  int g = bg & 31;
  int b = bg >> 5;
  int tid = threadIdx.x;
  float sum = 0.f, sq = 0.f;
  for (int e = pr * 8192 + tid; e < (pr + 1) * 8192; e += 256) {
    int p = e >> 3, cc = e & 7;
    float v = s[((size_t)(b * 16384 + p)) * 256 + g * 8 + cc];
    sum += v;
    sq += v * v;
  }
  __shared__ float rs[256], rq[256];
  rs[tid] = sum;
  rq[tid] = sq;
  __syncthreads();
  for (int st = 128; st > 0; st >>= 1) {
    if (tid < st) { rs[tid] += rs[tid + st]; rq[tid] += rq[tid + st]; }
    __syncthreads();
  }
  if (tid == 0) {
    part[(size_t)blk * 2 + 0] = rs[0];
    part[(size_t)blk * 2 + 1] = rq[0];
  }
}

__global__ void gn_final(const float* __restrict__ part,
                         float* __restrict__ stats) {
  int tid = threadIdx.x;
  if (tid < 64) {
    float s = 0.f, q = 0.f;
    for (int j = 0; j < 16; j++) {
      s += part[(size_t)(tid * 16 + j) * 2 + 0];
      q += part[(size_t)(tid * 16 + j) * 2 + 1];
    }
    float mu = s * (1.f / 131072.f);
    float var = q * (1.f / 131072.f) - mu * mu;
    stats[tid * 2 + 0] = mu;
    stats[tid * 2 + 1] = rsqrtf(var + EPSf);
  }
}

// ---------------- GN apply + GELU + transpose to NCHW ----------------
__global__ void gn_apply(const float* __restrict__ s,
                         const float* __restrict__ stats,
                         const float* __restrict__ gg,
                         const float* __restrict__ gb,
                         float* __restrict__ out) {
  __shared__ float tile[32][33];
  int p0 = blockIdx.x * 32, c0 = blockIdx.y * 32, b = blockIdx.z;
  int tx = threadIdx.x, tyy = threadIdx.y;
  int c = c0 + tx;
  float mu = stats[(b * 32 + (c >> 3)) * 2 + 0];
  float rstd = stats[(b * 32 + (c >> 3)) * 2 + 1];
  float gw = gg[c], bw = gb[c];
  for (int i = tyy; i < 32; i += 8) {
    float v = s[((size_t)(b * 16384 + p0 + i)) * 256 + c];
    v = (v - mu) * rstd * gw + bw;
    v = 0.5f * v * (1.f + erff(v * 0.70710678118654752f));
    tile[i][tx] = v;
  }
  __syncthreads();
  for (int i = tyy; i < 32; i += 8)
    out[((size_t)(b * 256 + c0 + i)) * 16384 + p0 + tx] = tile[tx][i];
}

// ---------------- launcher ----------------
extern "C" void kernel_launch(void* const* d_in, const int* in_sizes, int n_in,
                              void* d_out, int out_size, void* d_ws,
                              size_t ws_size, hipStream_t stream) {
  (void)in_sizes; (void)n_in; (void)out_size; (void)ws_size;
  const float* res2  = (const float*)d_in[0];
  const float* res3  = (const float*)d_in[1];
  const float* res4  = (const float*)d_in[2];
  const float* res5  = (const float*)d_in[3];
  const float* lemb  = (const float*)d_in[4];
  const float* off_W = (const float*)d_in[5];
  const float* off_b = (const float*)d_in[6];
  const float* aw_W  = (const float*)d_in[7];
  const float* aw_b  = (const float*)d_in[8];
  const float* val_W = (const float*)d_in[9];
  const float* val_b = (const float*)d_in[10];
  const float* out_W = (const float*)d_in[11];
  const float* out_b = (const float*)d_in[12];
  const float* ln1_g = (const float*)d_in[13];
  const float* ln1_b = (const float*)d_in[14];
  const float* fc1_W = (const float*)d_in[15];
  const float* fc1_b = (const float*)d_in[16];
  const float* fc2_W = (const float*)d_in[17];
  const float* fc2_b = (const float*)d_in[18];
  const float* ln2_g = (const float*)d_in[19];
  const float* ln2_b = (const float*)d_in[20];
  const float* lat_W = (const float*)d_in[21];
  const float* lat_b = (const float*)d_in[22];
  const float* sm_W  = (const float*)d_in[23];
  const float* sm_b  = (const float*)d_in[24];
  const float* gn_g  = (const float*)d_in[25];
  const float* gn_b  = (const float*)d_in[26];

  float* ws = (float*)d_ws;
  const size_t BNC = (size_t)Bn * Ntok * Cc;  // 2752512
  float* x      = ws;
  float* pe     = x + BNC;                    // 1376256
  float* q      = pe + (size_t)Ntok * Cc;
  float* value  = q + BNC;
  float* offb   = value + BNC;                // 2064384
  float* awl    = offb + (size_t)Bn * Ntok * 192;
  float* attn   = awl + (size_t)Bn * Ntok * 96;
  float* tmp    = attn + BNC;
  float* hbuf   = tmp + BNC;                  // 11010048 (also conv-input alias)
  float* tbuf   = hbuf;                       // conv input (B,HW,256), used after layers
  float* wtbuf  = hbuf + (size_t)Bn * Ntok * Ffn;
  float* gnpart = wtbuf + 256 * 2304;
  float* gnstat = gnpart + 2048;
  float* sbuf   = x;  // conv output aliases x..value region (dead by then)

  float* out_s  = (float*)d_out;
  float* out_o3 = out_s + (size_t)Bn * Cc * HW2;
  float* out_o4 = out_o3 + (size_t)Bn * Cc * 4096;
  float* out_o5 = out_o4 + (size_t)Bn * Cc * 1024;

  const int M = Bn * Ntok;  // 10752
  const int MB = M / 64;    // 168

  pe_kernel<<<1024, 256, 0, stream>>>(pe);
  flatten_kernel<<<1024, 256, 0, stream>>>(res3, res4, res5, lemb, x);

  for (int l = 0; l < 6; l++) {
    addpe_kernel<<<1024, 256, 0, stream>>>(x, pe, q);
    gemm_mfma<0><<<dim3(2, MB), 256, 0, stream>>>(
        x, val_W + (size_t)l * 65536, val_b + l * 256, value, M, 256, 256);
    gemm_mfma<0><<<dim3(2, MB), 256, 0, stream>>>(
        q, off_W + (size_t)l * 49152, off_b + l * 192, offb, M, 192, 256);
    gemm_mfma<0><<<dim3(1, MB), 256, 0, stream>>>(
        q, aw_W + (size_t)l * 24576, aw_b + l * 96, awl, M, 96, 256);
    msda_sample<<<10752, 256, 0, stream>>>(value, offb, awl, attn);
    gemm_mfma<0><<<dim3(2, MB), 256, 0, stream>>>(
        attn, out_W + (size_t)l * 65536, out_b + l * 256, tmp, M, 256, 256);
    ln_residual<<<M, 256, 0, stream>>>(x, tmp, ln1_g + l * 256, ln1_b + l * 256);
    gemm_mfma<1><<<dim3(8, MB), 256, 0, stream>>>(
        x, fc1_W + (size_t)l * 262144, fc1_b + l * 1024, hbuf, M, 1024, 256);
    gemm_mfma<0><<<dim3(2, MB), 256, 0, stream>>>(
        hbuf, fc2_W + (size_t)l * 262144, fc2_b + l * 256, tmp, M, 256, 1024);
    ln_residual<<<M, 256, 0, stream>>>(x, tmp, ln2_g + l * 256, ln2_b + l * 256);
  }

  // token outputs (read x) — must precede sbuf (aliases x) writes
  rows_to_nchw<<<dim3(128, 8, 2), dim3(32, 8), 0, stream>>>(x, out_o3, 0, 4096);
  rows_to_nchw<<<dim3(32, 8, 2), dim3(32, 8), 0, stream>>>(x, out_o4, 4096, 1024);
  rows_to_nchw<<<dim3(8, 8, 2), dim3(32, 8), 0, stream>>>(x, out_o5, 5120, 256);

  // FPN tail
  gemm_tn_mfma<<<dim3(2, 512), 256, 0, stream>>>(res2, lat_W, lat_b, tbuf);
  upsample_add<<<32768, 256, 0, stream>>>(x, tbuf);
  wt_transpose<<<1024, 256, 0, stream>>>(sm_W, wtbuf);
  conv3x3_mfma<<<dim3(2, 512), 256, 0, stream>>>(tbuf, wtbuf, sm_b, sbuf);
  gn_partial<<<1024, 256, 0, stream>>>(sbuf, gnpart);
  gn_final<<<1, 64, 0, stream>>>(gnpart, gnstat);
  gn_apply<<<dim3(512, 8, 2), dim3(32, 8), 0, stream>>>(sbuf, gnstat, gn_g,
                                                        gn_b, out_s);
}

// Round 4
// 1450.323 us; speedup vs baseline: 3.3945x; 1.2244x over previous
//
#include <hip/hip_runtime.h>

// ---------------- constants ----------------
namespace {
constexpr int Bn   = 2;
constexpr int Cc   = 256;
constexpr int Ntok = 5376;      // 4096 + 1024 + 256
constexpr int Ffn  = 1024;
constexpr int HW2  = 128 * 128; // res2 spatial
constexpr float EPSf = 1e-5f;
}

typedef __attribute__((ext_vector_type(8))) short bf16x8;
typedef __attribute__((ext_vector_type(4))) float f32x4;

__device__ inline unsigned short f2bf(float x) {
  unsigned u = __float_as_uint(x);
  return (unsigned short)((u + 0x7fffu + ((u >> 16) & 1u)) >> 16);
}
__device__ inline float bf2f(unsigned short b) {
  return __uint_as_float((unsigned)b << 16);
}

// store one 16B chunk (8 bf16) to LDS, XOR-swizzled granule
__device__ inline void store_chunk_f32(unsigned short* lds, int row, int g,
                                       const float* v8) {
  int sg = g ^ (row & 7);
  unsigned short tmp[8];
#pragma unroll
  for (int j = 0; j < 8; j++) tmp[j] = f2bf(v8[j]);
  *reinterpret_cast<uint4*>(&lds[row * 64 + sg * 8]) =
      *reinterpret_cast<const uint4*>(tmp);
}
__device__ inline void store_chunk_bf(unsigned short* lds, int row, int g,
                                      uint4 v) {
  int sg = g ^ (row & 7);
  *reinterpret_cast<uint4*>(&lds[row * 64 + sg * 8]) = v;
}

// ---------------- positional encoding (bf16 out) ----------------
__global__ void pe_kernel(unsigned short* __restrict__ pe) {
  for (int i = blockIdx.x * blockDim.x + threadIdx.x; i < Ntok * Cc;
       i += gridDim.x * blockDim.x) {
    int c = i & 255;
    int p = i >> 8;
    int li = (p < 4096) ? 0 : ((p < 5120) ? 1 : 2);
    int start = (li == 0) ? 0 : ((li == 1) ? 4096 : 5120);
    int W = 64 >> li;
    int sp = p - start;
    int shift = 6 - li;
    int iy = sp >> shift;
    int ix = sp & (W - 1);
    int j = c & 63;
    int sel = c >> 6;
    float div = expf(-(float)j * (9.210340371976184f / 64.f));
    float coord = (sel < 2) ? (float)iy : (float)ix;
    float arg = coord * div;
    pe[i] = f2bf((sel & 1) ? cosf(arg) : sinf(arg));
  }
}

// ---------------- flatten + level_embed -> x fp32 + xb bf16 ----------------
__global__ void flatten_kernel(const float* __restrict__ r3,
                               const float* __restrict__ r4,
                               const float* __restrict__ r5,
                               const float* __restrict__ lemb,
                               float* __restrict__ x,
                               unsigned short* __restrict__ xb) {
  for (int i = blockIdx.x * blockDim.x + threadIdx.x; i < Bn * Ntok * Cc;
       i += gridDim.x * blockDim.x) {
    int c = i & 255;
    int rest = i >> 8;
    int p = rest % Ntok;
    int b = rest / Ntok;
    int li = (p < 4096) ? 0 : ((p < 5120) ? 1 : 2);
    int start = (li == 0) ? 0 : ((li == 1) ? 4096 : 5120);
    int size = (li == 0) ? 4096 : ((li == 1) ? 1024 : 256);
    const float* f = (li == 0) ? r3 : ((li == 1) ? r4 : r5);
    int sp = p - start;
    float v = f[((size_t)(b * Cc + c)) * size + sp] + lemb[li * Cc + c];
    x[i] = v;
    xb[i] = f2bf(v);
  }
}

// ---------------- q = x + pe -> bf16 ----------------
__global__ void addpe_kernel(const float* __restrict__ x,
                             const unsigned short* __restrict__ pe,
                             unsigned short* __restrict__ qb) {
  const int NPC = Ntok * Cc;
  int n4 = Bn * NPC / 4;
  for (int i = blockIdx.x * blockDim.x + threadIdx.x; i < n4;
       i += gridDim.x * blockDim.x) {
    int e = i * 4;
    int pc = (e >= NPC) ? e - NPC : e;
    float4 xv = *reinterpret_cast<const float4*>(&x[e]);
    ushort4 pv = *reinterpret_cast<const ushort4*>(&pe[pc]);
    unsigned short t[4] = {f2bf(xv.x + bf2f(pv.x)), f2bf(xv.y + bf2f(pv.y)),
                           f2bf(xv.z + bf2f(pv.z)), f2bf(xv.w + bf2f(pv.w))};
    *reinterpret_cast<uint2*>(&qb[e]) = *reinterpret_cast<const uint2*>(t);
  }
}

// =================================================================
// MFMA GEMM: out(M,N) = A(M,K)bf16 @ W(N,K)^T fp32 + bias.
// BM=64, BN=128, BK=64, 256 threads = 4 waves (2x2), 16x16x32 mfma.
// =================================================================
template <int ACT, int OBF>
__global__ __launch_bounds__(256) void gemm_mfma_b(
    const unsigned short* __restrict__ A, const float* __restrict__ W,
    const float* __restrict__ bias, void* __restrict__ outp,
    int M, int N, int K) {
  __shared__ unsigned short As[64 * 64];
  __shared__ unsigned short Ws[128 * 64];
  const int tid = threadIdx.x;
  const int m0 = blockIdx.y * 64, n0 = blockIdx.x * 128;
  const int wid = tid >> 6, lane = tid & 63;
  const int wm = wid >> 1, wn = wid & 1;
  const int lr = lane & 15, lh = lane >> 4;
  f32x4 acc[2][4];
#pragma unroll
  for (int i = 0; i < 2; i++)
#pragma unroll
    for (int j = 0; j < 4; j++) acc[i][j] = f32x4{0.f, 0.f, 0.f, 0.f};

  for (int k0 = 0; k0 < K; k0 += 64) {
#pragma unroll
    for (int i = 0; i < 2; i++) {
      int c = tid + i * 256;
      int row = c >> 3, g = c & 7;
      uint4 v = *reinterpret_cast<const uint4*>(
          &A[(size_t)(m0 + row) * K + k0 + g * 8]);
      store_chunk_bf(As, row, g, v);
    }
#pragma unroll
    for (int i = 0; i < 4; i++) {
      int c = tid + i * 256;
      int row = c >> 3, g = c & 7;
      int n = n0 + row;
      float v8[8] = {0.f, 0.f, 0.f, 0.f, 0.f, 0.f, 0.f, 0.f};
      if (n < N) {
        const float4* src =
            reinterpret_cast<const float4*>(&W[(size_t)n * K + k0 + g * 8]);
        float4 v0 = src[0], v1 = src[1];
        v8[0] = v0.x; v8[1] = v0.y; v8[2] = v0.z; v8[3] = v0.w;
        v8[4] = v1.x; v8[5] = v1.y; v8[6] = v1.z; v8[7] = v1.w;
      }
      store_chunk_f32(Ws, row, g, v8);
    }
    __syncthreads();
    bf16x8 af[2][2], bfr[4][2];
#pragma unroll
    for (int mi = 0; mi < 2; mi++) {
      int r = wm * 32 + mi * 16 + lr;
#pragma unroll
      for (int s = 0; s < 2; s++) {
        int g = s * 4 + lh;
        af[mi][s] =
            *reinterpret_cast<const bf16x8*>(&As[r * 64 + (g ^ (r & 7)) * 8]);
      }
    }
#pragma unroll
    for (int nj = 0; nj < 4; nj++) {
      int r = wn * 64 + nj * 16 + lr;
#pragma unroll
      for (int s = 0; s < 2; s++) {
        int g = s * 4 + lh;
        bfr[nj][s] =
            *reinterpret_cast<const bf16x8*>(&Ws[r * 64 + (g ^ (r & 7)) * 8]);
      }
    }
#pragma unroll
    for (int mi = 0; mi < 2; mi++)
#pragma unroll
      for (int nj = 0; nj < 4; nj++) {
        acc[mi][nj] = __builtin_amdgcn_mfma_f32_16x16x32_bf16(
            af[mi][0], bfr[nj][0], acc[mi][nj], 0, 0, 0);
        acc[mi][nj] = __builtin_amdgcn_mfma_f32_16x16x32_bf16(
            af[mi][1], bfr[nj][1], acc[mi][nj], 0, 0, 0);
      }
    __syncthreads();
  }
#pragma unroll
  for (int mi = 0; mi < 2; mi++) {
    int row = m0 + wm * 32 + mi * 16 + lh * 4;
#pragma unroll
    for (int nj = 0; nj < 4; nj++) {
      int col = n0 + wn * 64 + nj * 16 + lr;
      if (col >= N) continue;
      float b = bias[col];
#pragma unroll
      for (int r = 0; r < 4; r++) {
        float v = acc[mi][nj][r] + b;
        if (ACT) v = fmaxf(v, 0.f);
        if (OBF)
          ((unsigned short*)outp)[(size_t)(row + r) * N + col] = f2bf(v);
        else
          ((float*)outp)[(size_t)(row + r) * N + col] = v;
      }
    }
  }
}

// -------- fused off(192)+aw(96) GEMM over qb: virtual N=288 --------
__global__ __launch_bounds__(256) void gemm_offaw(
    const unsigned short* __restrict__ A, const float* __restrict__ offW,
    const float* __restrict__ offB, const float* __restrict__ awW,
    const float* __restrict__ awB, float* __restrict__ offO,
    float* __restrict__ awO, int M) {
  __shared__ unsigned short As[64 * 64];
  __shared__ unsigned short Ws[128 * 64];
  const int tid = threadIdx.x;
  const int m0 = blockIdx.y * 64, n0 = blockIdx.x * 128;
  const int wid = tid >> 6, lane = tid & 63;
  const int wm = wid >> 1, wn = wid & 1;
  const int lr = lane & 15, lh = lane >> 4;
  f32x4 acc[2][4];
#pragma unroll
  for (int i = 0; i < 2; i++)
#pragma unroll
    for (int j = 0; j < 4; j++) acc[i][j] = f32x4{0.f, 0.f, 0.f, 0.f};

  for (int k0 = 0; k0 < 256; k0 += 64) {
#pragma unroll
    for (int i = 0; i < 2; i++) {
      int c = tid + i * 256;
      int row = c >> 3, g = c & 7;
      uint4 v = *reinterpret_cast<const uint4*>(
          &A[(size_t)(m0 + row) * 256 + k0 + g * 8]);
      store_chunk_bf(As, row, g, v);
    }
#pragma unroll
    for (int i = 0; i < 4; i++) {
      int c = tid + i * 256;
      int row = c >> 3, g = c & 7;
      int n = n0 + row;
      float v8[8] = {0.f, 0.f, 0.f, 0.f, 0.f, 0.f, 0.f, 0.f};
      const float* src = nullptr;
      if (n < 192) src = &offW[(size_t)n * 256 + k0 + g * 8];
      else if (n < 288) src = &awW[(size_t)(n - 192) * 256 + k0 + g * 8];
      if (src) {
        float4 v0 = reinterpret_cast<const float4*>(src)[0];
        float4 v1 = reinterpret_cast<const float4*>(src)[1];
        v8[0] = v0.x; v8[1] = v0.y; v8[2] = v0.z; v8[3] = v0.w;
        v8[4] = v1.x; v8[5] = v1.y; v8[6] = v1.z; v8[7] = v1.w;
      }
      store_chunk_f32(Ws, row, g, v8);
    }
    __syncthreads();
    bf16x8 af[2][2], bfr[4][2];
#pragma unroll
    for (int mi = 0; mi < 2; mi++) {
      int r = wm * 32 + mi * 16 + lr;
#pragma unroll
      for (int s = 0; s < 2; s++) {
        int g = s * 4 + lh;
        af[mi][s] =
            *reinterpret_cast<const bf16x8*>(&As[r * 64 + (g ^ (r & 7)) * 8]);
      }
    }
#pragma unroll
    for (int nj = 0; nj < 4; nj++) {
      int r = wn * 64 + nj * 16 + lr;
#pragma unroll
      for (int s = 0; s < 2; s++) {
        int g = s * 4 + lh;
        bfr[nj][s] =
            *reinterpret_cast<const bf16x8*>(&Ws[r * 64 + (g ^ (r & 7)) * 8]);
      }
    }
#pragma unroll
    for (int mi = 0; mi < 2; mi++)
#pragma unroll
      for (int nj = 0; nj < 4; nj++) {
        acc[mi][nj] = __builtin_amdgcn_mfma_f32_16x16x32_bf16(
            af[mi][0], bfr[nj][0], acc[mi][nj], 0, 0, 0);
        acc[mi][nj] = __builtin_amdgcn_mfma_f32_16x16x32_bf16(
            af[mi][1], bfr[nj][1], acc[mi][nj], 0, 0, 0);
      }
    __syncthreads();
  }
#pragma unroll
  for (int mi = 0; mi < 2; mi++) {
    int row = m0 + wm * 32 + mi * 16 + lh * 4;
#pragma unroll
    for (int nj = 0; nj < 4; nj++) {
      int col = n0 + wn * 64 + nj * 16 + lr;
      if (col >= 288) continue;
      float b = (col < 192) ? offB[col] : awB[col - 192];
#pragma unroll
      for (int r = 0; r < 4; r++) {
        float v = acc[mi][nj][r] + b;
        if (col < 192)
          offO[(size_t)(row + r) * 192 + col] = v;
        else
          awO[(size_t)(row + r) * 96 + col - 192] = v;
      }
    }
  }
}

// ------------- implicit-GEMM 3x3 conv, bf16 in, fp32 out -------------
__global__ __launch_bounds__(256) void conv3x3_mfma(
    const unsigned short* __restrict__ T, const unsigned short* __restrict__ Wt,
    const float* __restrict__ bias, float* __restrict__ out) {
  __shared__ unsigned short As[64 * 64];
  __shared__ unsigned short Ws[128 * 64];
  const int tid = threadIdx.x;
  const int m0 = blockIdx.y * 64, n0 = blockIdx.x * 128;
  const int b = m0 >> 14;
  const int p0 = m0 & 16383;
  const int y = p0 >> 7;
  const int x0 = p0 & 127;
  const int wid = tid >> 6, lane = tid & 63;
  const int wm = wid >> 1, wn = wid & 1;
  const int lr = lane & 15, lh = lane >> 4;
  f32x4 acc[2][4];
#pragma unroll
  for (int i = 0; i < 2; i++)
#pragma unroll
    for (int j = 0; j < 4; j++) acc[i][j] = f32x4{0.f, 0.f, 0.f, 0.f};

  for (int k0 = 0; k0 < 2304; k0 += 64) {
    int tap = k0 >> 8;
    int cb = k0 & 255;
    int dy = tap / 3 - 1, dx = tap % 3 - 1;
    int yy = y + dy;
#pragma unroll
    for (int i = 0; i < 2; i++) {
      int c = tid + i * 256;
      int row = c >> 3, g = c & 7;
      int xx = x0 + row + dx;
      uint4 v = uint4{0, 0, 0, 0};
      if (yy >= 0 && yy < 128 && xx >= 0 && xx < 128)
        v = *reinterpret_cast<const uint4*>(
            &T[((size_t)(b * 16384 + yy * 128 + xx)) * 256 + cb + g * 8]);
      store_chunk_bf(As, row, g, v);
    }
#pragma unroll
    for (int i = 0; i < 4; i++) {
      int c = tid + i * 256;
      int row = c >> 3, g = c & 7;
      uint4 v = *reinterpret_cast<const uint4*>(
          &Wt[(size_t)(n0 + row) * 2304 + k0 + g * 8]);
      store_chunk_bf(Ws, row, g, v);
    }
    __syncthreads();
    bf16x8 af[2][2], bfr[4][2];
#pragma unroll
    for (int mi = 0; mi < 2; mi++) {
      int r = wm * 32 + mi * 16 + lr;
#pragma unroll
      for (int s = 0; s < 2; s++) {
        int g = s * 4 + lh;
        af[mi][s] =
            *reinterpret_cast<const bf16x8*>(&As[r * 64 + (g ^ (r & 7)) * 8]);
      }
    }
#pragma unroll
    for (int nj = 0; nj < 4; nj++) {
      int r = wn * 64 + nj * 16 + lr;
#pragma unroll
      for (int s = 0; s < 2; s++) {
        int g = s * 4 + lh;
        bfr[nj][s] =
            *reinterpret_cast<const bf16x8*>(&Ws[r * 64 + (g ^ (r & 7)) * 8]);
      }
    }
#pragma unroll
    for (int mi = 0; mi < 2; mi++)
#pragma unroll
      for (int nj = 0; nj < 4; nj++) {
        acc[mi][nj] = __builtin_amdgcn_mfma_f32_16x16x32_bf16(
            af[mi][0], bfr[nj][0], acc[mi][nj], 0, 0, 0);
        acc[mi][nj] = __builtin_amdgcn_mfma_f32_16x16x32_bf16(
            af[mi][1], bfr[nj][1], acc[mi][nj], 0, 0, 0);
      }
    __syncthreads();
  }
#pragma unroll
  for (int mi = 0; mi < 2; mi++) {
    int row = m0 + wm * 32 + mi * 16 + lh * 4;
#pragma unroll
    for (int nj = 0; nj < 4; nj++) {
      int col = n0 + wn * 64 + nj * 16 + lr;
      float b = bias[col];
#pragma unroll
      for (int r = 0; r < 4; r++)
        out[(size_t)(row + r) * 256 + col] = acc[mi][nj][r] + b;
    }
  }
}

// ------------- TN GEMM (1x1 lateral conv): A=(B,256,HW) NCHW fp32, out bf16 -------------
__global__ __launch_bounds__(256) void gemm_tn_mfma(
    const float* __restrict__ A, const float* __restrict__ W,
    const float* __restrict__ bias, unsigned short* __restrict__ out) {
  __shared__ unsigned short As[64 * 64];
  __shared__ unsigned short Ws[128 * 64];
  const int tid = threadIdx.x;
  const int m0 = blockIdx.y * 64, n0 = blockIdx.x * 128;
  const int b = m0 >> 14;
  const int p0 = m0 & 16383;
  const int wid = tid >> 6, lane = tid & 63;
  const int wm = wid >> 1, wn = wid & 1;
  const int lr = lane & 15, lh = lane >> 4;
  f32x4 acc[2][4];
#pragma unroll
  for (int i = 0; i < 2; i++)
#pragma unroll
    for (int j = 0; j < 4; j++) acc[i][j] = f32x4{0.f, 0.f, 0.f, 0.f};

  for (int k0 = 0; k0 < 256; k0 += 64) {
#pragma unroll
    for (int i = 0; i < 2; i++) {
      int c = tid + i * 256;
      int row = c & 63, g = c >> 6;
      float v8[8];
#pragma unroll
      for (int j = 0; j < 8; j++)
        v8[j] = A[(size_t)(b * 256 + k0 + g * 8 + j) * 16384 + p0 + row];
      store_chunk_f32(As, row, g, v8);
    }
#pragma unroll
    for (int i = 0; i < 4; i++) {
      int c = tid + i * 256;
      int row = c >> 3, g = c & 7;
      const float4* src =
          reinterpret_cast<const float4*>(&W[(size_t)(n0 + row) * 256 + k0 + g * 8]);
      float4 v0 = src[0], v1 = src[1];
      float v8[8] = {v0.x, v0.y, v0.z, v0.w, v1.x, v1.y, v1.z, v1.w};
      store_chunk_f32(Ws, row, g, v8);
    }
    __syncthreads();
    bf16x8 af[2][2], bfr[4][2];
#pragma unroll
    for (int mi = 0; mi < 2; mi++) {
      int r = wm * 32 + mi * 16 + lr;
#pragma unroll
      for (int s = 0; s < 2; s++) {
        int g = s * 4 + lh;
        af[mi][s] =
            *reinterpret_cast<const bf16x8*>(&As[r * 64 + (g ^ (r & 7)) * 8]);
      }
    }
#pragma unroll
    for (int nj = 0; nj < 4; nj++) {
      int r = wn * 64 + nj * 16 + lr;
#pragma unroll
      for (int s = 0; s < 2; s++) {
        int g = s * 4 + lh;
        bfr[nj][s] =
            *reinterpret_cast<const bf16x8*>(&Ws[r * 64 + (g ^ (r & 7)) * 8]);
      }
    }
#pragma unroll
    for (int mi = 0; mi < 2; mi++)
#pragma unroll
      for (int nj = 0; nj < 4; nj++) {
        acc[mi][nj] = __builtin_amdgcn_mfma_f32_16x16x32_bf16(
            af[mi][0], bfr[nj][0], acc[mi][nj], 0, 0, 0);
        acc[mi][nj] = __builtin_amdgcn_mfma_f32_16x16x32_bf16(
            af[mi][1], bfr[nj][1], acc[mi][nj], 0, 0, 0);
      }
    __syncthreads();
  }
#pragma unroll
  for (int mi = 0; mi < 2; mi++) {
    int row = m0 + wm * 32 + mi * 16 + lh * 4;
#pragma unroll
    for (int nj = 0; nj < 4; nj++) {
      int col = n0 + wn * 64 + nj * 16 + lr;
      float b = bias[col];
#pragma unroll
      for (int r = 0; r < 4; r++)
        out[(size_t)(row + r) * 256 + col] = f2bf(acc[mi][nj][r] + b);
    }
  }
}

// ---------------- deformable sampling + fused softmax (bf16 value) ----------------
__global__ __launch_bounds__(256) void msda_sample(
    const unsigned short* __restrict__ value, const float* __restrict__ off,
    const float* __restrict__ awl, unsigned short* __restrict__ attn) {
  int gid = blockIdx.x * 8 + (threadIdx.x >> 5);
  int lane = threadIdx.x & 31;
  int h = gid & 7;
  int bn = gid >> 3;
  int n = bn % Ntok;
  int b = bn / Ntok;

  int li0 = (n < 4096) ? 0 : ((n < 5120) ? 1 : 2);
  int start0 = (li0 == 0) ? 0 : ((li0 == 1) ? 4096 : 5120);
  int shift = 6 - li0;
  int Wn = 1 << shift;
  int sp = n - start0;
  int iy = sp >> shift;
  int ix = sp & (Wn - 1);
  float refx = (ix + 0.5f) / (float)Wn;
  float refy = (iy + 0.5f) / (float)Wn;

  const float* ap = awl + (size_t)bn * 96 + h * 12;
  float lg[12];
  float mx = -1e30f;
#pragma unroll
  for (int j = 0; j < 12; j++) { lg[j] = ap[j]; mx = fmaxf(mx, lg[j]); }
  float ssum = 0.f;
#pragma unroll
  for (int j = 0; j < 12; j++) { lg[j] = expf(lg[j] - mx); ssum += lg[j]; }
  float inv = 1.f / ssum;

  const float* op = off + (size_t)bn * 192 + h * 24;
  float acc = 0.f;
#pragma unroll
  for (int li = 0; li < 3; li++) {
    int HWl = 64 >> li;
    int st = (li == 0) ? 0 : ((li == 1) ? 4096 : 5120);
    const unsigned short* vb =
        value + ((size_t)(b * Ntok + st) * 8 + h) * 32 + lane;
#pragma unroll
    for (int p = 0; p < 4; p++) {
      float ox = op[(li * 4 + p) * 2 + 0];
      float oy = op[(li * 4 + p) * 2 + 1];
      float lx = refx + ox / (float)HWl;
      float ly = refy + oy / (float)HWl;
      float fx = lx * (float)HWl - 0.5f;
      float fy = ly * (float)HWl - 0.5f;
      float x0f = floorf(fx), y0f = floorf(fy);
      float wx = fx - x0f, wy = fy - y0f;
      int ix0 = (int)x0f, iy0 = (int)y0f;
      float w = lg[li * 4 + p] * inv;
      float w00 = w * (1.f - wx) * (1.f - wy);
      float w01 = w * wx * (1.f - wy);
      float w10 = w * (1.f - wx) * wy;
      float w11 = w * wx * wy;
      if (ix0 >= 0 && ix0 < HWl && iy0 >= 0 && iy0 < HWl)
        acc += w00 * bf2f(vb[(size_t)(iy0 * HWl + ix0) * 256]);
      if (ix0 + 1 >= 0 && ix0 + 1 < HWl && iy0 >= 0 && iy0 < HWl)
        acc += w01 * bf2f(vb[(size_t)(iy0 * HWl + ix0 + 1) * 256]);
      if (ix0 >= 0 && ix0 < HWl && iy0 + 1 >= 0 && iy0 + 1 < HWl)
        acc += w10 * bf2f(vb[(size_t)((iy0 + 1) * HWl + ix0) * 256]);
      if (ix0 + 1 >= 0 && ix0 + 1 < HWl && iy0 + 1 >= 0 && iy0 + 1 < HWl)
        acc += w11 * bf2f(vb[(size_t)((iy0 + 1) * HWl + ix0 + 1) * 256]);
    }
  }
  attn[((size_t)bn * 8 + h) * 32 + lane] = f2bf(acc);
}

// ---------------- residual add + LayerNorm, wave-per-row ----------------
// writes x fp32 (in place) and xb bf16
__global__ __launch_bounds__(256) void ln_residual(
    float* __restrict__ x, unsigned short* __restrict__ xb,
    const float* __restrict__ r, const float* __restrict__ g,
    const float* __restrict__ bta) {
  int w = threadIdx.x >> 6, lane = threadIdx.x & 63;
  int row = blockIdx.x * 4 + w;
  size_t base = (size_t)row * 256 + lane * 4;
  float4 v = *reinterpret_cast<const float4*>(&x[base]);
  float4 rr = *reinterpret_cast<const float4*>(&r[base]);
  v.x += rr.x; v.y += rr.y; v.z += rr.z; v.w += rr.w;
  float s = v.x + v.y + v.z + v.w;
#pragma unroll
  for (int o = 32; o > 0; o >>= 1) s += __shfl_xor(s, o);
  float mu = s * (1.f / 256.f);
  float4 d = {v.x - mu, v.y - mu, v.z - mu, v.w - mu};
  float sq = d.x * d.x + d.y * d.y + d.z * d.z + d.w * d.w;
#pragma unroll
  for (int o = 32; o > 0; o >>= 1) sq += __shfl_xor(sq, o);
  float rstd = rsqrtf(sq * (1.f / 256.f) + EPSf);
  float4 gv = *reinterpret_cast<const float4*>(&g[lane * 4]);
  float4 bv = *reinterpret_cast<const float4*>(&bta[lane * 4]);
  float4 o4 = {d.x * rstd * gv.x + bv.x, d.y * rstd * gv.y + bv.y,
               d.z * rstd * gv.z + bv.z, d.w * rstd * gv.w + bv.w};
  *reinterpret_cast<float4*>(&x[base]) = o4;
  unsigned short t[4] = {f2bf(o4.x), f2bf(o4.y), f2bf(o4.z), f2bf(o4.w)};
  *reinterpret_cast<uint2*>(&xb[base]) = *reinterpret_cast<const uint2*>(t);
}

// ---------------- bilinear 64->128 upsample, += into bf16 t ----------------
__global__ __launch_bounds__(256) void upsample_add(
    const float* __restrict__ xrows, unsigned short* __restrict__ t) {
  int bp = blockIdx.x;
  int c = threadIdx.x;
  int b = bp >> 14;
  int p = bp & 16383;
  int Y = p >> 7, X = p & 127;
  float yc = Y * 0.5f - 0.25f;
  float y0f = floorf(yc);
  float wy = yc - y0f;
  int y0 = (int)y0f, y1 = y0 + 1;
  int y0c = min(max(y0, 0), 63), y1c = min(max(y1, 0), 63);
  float xc = X * 0.5f - 0.25f;
  float x0f = floorf(xc);
  float wx = xc - x0f;
  int xq0 = (int)x0f, xq1 = xq0 + 1;
  int x0c = min(max(xq0, 0), 63), x1c = min(max(xq1, 0), 63);
  const float* base = xrows + (size_t)b * Ntok * 256;
  float v00 = base[(size_t)(y0c * 64 + x0c) * 256 + c];
  float v01 = base[(size_t)(y0c * 64 + x1c) * 256 + c];
  float v10 = base[(size_t)(y1c * 64 + x0c) * 256 + c];
  float v11 = base[(size_t)(y1c * 64 + x1c) * 256 + c];
  float v = (1.f - wy) * ((1.f - wx) * v00 + wx * v01) +
            wy * ((1.f - wx) * v10 + wx * v11);
  size_t idx = (size_t)bp * 256 + c;
  t[idx] = f2bf(bf2f(t[idx]) + v);
}

// ---------------- token rows -> NCHW output (tiled transpose) ----------------
__global__ void rows_to_nchw(const float* __restrict__ xrows,
                             float* __restrict__ out, int start, int size) {
  __shared__ float tile[32][33];
  int p0 = blockIdx.x * 32, c0 = blockIdx.y * 32, b = blockIdx.z;
  int tx = threadIdx.x, tyy = threadIdx.y;
  for (int i = tyy; i < 32; i += 8)
    tile[i][tx] = xrows[((size_t)(b * Ntok + start + p0 + i)) * 256 + c0 + tx];
  __syncthreads();
  for (int i = tyy; i < 32; i += 8)
    out[((size_t)(b * 256 + c0 + i)) * size + p0 + tx] = tile[tx][i];
}

// ---------------- conv weight repack (O,C,3,3) -> bf16 (O, tap*256+c) ----------------
__global__ void wt_transpose(const float* __restrict__ w,
                             unsigned short* __restrict__ wt) {
  for (int i = blockIdx.x * blockDim.x + threadIdx.x; i < 256 * 2304;
       i += gridDim.x * blockDim.x) {
    int o = i / 2304;
    int r = i % 2304;
    int tap = r >> 8;
    int c = r & 255;
    wt[i] = f2bf(w[((size_t)(o * 256 + c)) * 9 + tap]);
  }
}

// ---------------- GroupNorm partial sums ----------------
__global__ __launch_bounds__(256) void gn_partial(
    const float* __restrict__ s, float* __restrict__ part) {
  int blk = blockIdx.x;
  int pr = blk & 15;
  int bg = blk >> 4;
  int g = bg & 31;
  int b = bg >> 5;
  int tid = threadIdx.x;
  float sum = 0.f, sq = 0.f;
  for (int e = pr * 8192 + tid; e < (pr + 1) * 8192; e += 256) {
    int p = e >> 3, cc = e & 7;
    float v = s[((size_t)(b * 16384 + p)) * 256 + g * 8 + cc];
    sum += v;
    sq += v * v;
  }
  __shared__ float rs[256], rq[256];
  rs[tid] = sum;
  rq[tid] = sq;
  __syncthreads();
  for (int st = 128; st > 0; st >>= 1) {
    if (tid < st) { rs[tid] += rs[tid + st]; rq[tid] += rq[tid + st]; }
    __syncthreads();
  }
  if (tid == 0) {
    part[(size_t)blk * 2 + 0] = rs[0];
    part[(size_t)blk * 2 + 1] = rq[0];
  }
}

__global__ void gn_final(const float* __restrict__ part,
                         float* __restrict__ stats) {
  int tid = threadIdx.x;
  if (tid < 64) {
    float s = 0.f, q = 0.f;
    for (int j = 0; j < 16; j++) {
      s += part[(size_t)(tid * 16 + j) * 2 + 0];
      q += part[(size_t)(tid * 16 + j) * 2 + 1];
    }
    float mu = s * (1.f / 131072.f);
    float var = q * (1.f / 131072.f) - mu * mu;
    stats[tid * 2 + 0] = mu;
    stats[tid * 2 + 1] = rsqrtf(var + EPSf);
  }
}

// ---------------- GN apply + GELU + transpose to NCHW ----------------
__global__ void gn_apply(const float* __restrict__ s,
                         const float* __restrict__ stats,
                         const float* __restrict__ gg,
                         const float* __restrict__ gb,
                         float* __restrict__ out) {
  __shared__ float tile[32][33];
  int p0 = blockIdx.x * 32, c0 = blockIdx.y * 32, b = blockIdx.z;
  int tx = threadIdx.x, tyy = threadIdx.y;
  int c = c0 + tx;
  float mu = stats[(b * 32 + (c >> 3)) * 2 + 0];
  float rstd = stats[(b * 32 + (c >> 3)) * 2 + 1];
  float gw = gg[c], bw = gb[c];
  for (int i = tyy; i < 32; i += 8) {
    float v = s[((size_t)(b * 16384 + p0 + i)) * 256 + c];
    v = (v - mu) * rstd * gw + bw;
    v = 0.5f * v * (1.f + erff(v * 0.70710678118654752f));
    tile[i][tx] = v;
  }
  __syncthreads();
  for (int i = tyy; i < 32; i += 8)
    out[((size_t)(b * 256 + c0 + i)) * 16384 + p0 + tx] = tile[tx][i];
}

// ---------------- launcher ----------------
extern "C" void kernel_launch(void* const* d_in, const int* in_sizes, int n_in,
                              void* d_out, int out_size, void* d_ws,
                              size_t ws_size, hipStream_t stream) {
  (void)in_sizes; (void)n_in; (void)out_size; (void)ws_size;
  const float* res2  = (const float*)d_in[0];
  const float* res3  = (const float*)d_in[1];
  const float* res4  = (const float*)d_in[2];
  const float* res5  = (const float*)d_in[3];
  const float* lemb  = (const float*)d_in[4];
  const float* off_W = (const float*)d_in[5];
  const float* off_b = (const float*)d_in[6];
  const float* aw_W  = (const float*)d_in[7];
  const float* aw_b  = (const float*)d_in[8];
  const float* val_W = (const float*)d_in[9];
  const float* val_b = (const float*)d_in[10];
  const float* out_W = (const float*)d_in[11];
  const float* out_b = (const float*)d_in[12];
  const float* ln1_g = (const float*)d_in[13];
  const float* ln1_b = (const float*)d_in[14];
  const float* fc1_W = (const float*)d_in[15];
  const float* fc1_b = (const float*)d_in[16];
  const float* fc2_W = (const float*)d_in[17];
  const float* fc2_b = (const float*)d_in[18];
  const float* ln2_g = (const float*)d_in[19];
  const float* ln2_b = (const float*)d_in[20];
  const float* lat_W = (const float*)d_in[21];
  const float* lat_b = (const float*)d_in[22];
  const float* sm_W  = (const float*)d_in[23];
  const float* sm_b  = (const float*)d_in[24];
  const float* gn_g  = (const float*)d_in[25];
  const float* gn_b  = (const float*)d_in[26];

  float* ws = (float*)d_ws;
  const size_t BNC = (size_t)Bn * Ntok * Cc;  // 2752512
  // layout (float units); bf16 buffers take count/2 floats
  float*          x      = ws;                               // 0       (2752512)
  unsigned short* xb     = (unsigned short*)(ws + 2752512);  //         (1376256)
  unsigned short* peb    = (unsigned short*)(ws + 4128768);  //         (688128)
  unsigned short* qb     = (unsigned short*)(ws + 4816896);  //         (1376256)
  unsigned short* valueb = (unsigned short*)(ws + 6193152);  //         (1376256)
  float*          offb   = ws + 7569408;                     //         (2064384)
  float*          awl    = ws + 9633792;                     //         (1032192)
  unsigned short* attnb  = (unsigned short*)(ws + 10665984); //         (1376256)
  float*          tmp    = ws + 12042240;                    //         (2752512)
  unsigned short* hb     = (unsigned short*)(ws + 14794752); //         (5505024)
  unsigned short* tbuf   = hb;  // conv input aliases hb (dead after layers)
  unsigned short* wtbuf  = (unsigned short*)(ws + 20299776); //         (294912)
  float*          gnpart = ws + 20594688;                    //         (2048)
  float*          gnstat = ws + 20596736;                    //         (128)
  // total 20596864 floats = 82.4 MB (same footprint as passing R2)
  float*          sbuf   = ws;  // conv out fp32 (8388608 f): spans dead
                                // x..valueb + first part of dead offb

  float* out_s  = (float*)d_out;
  float* out_o3 = out_s + (size_t)Bn * Cc * HW2;
  float* out_o4 = out_o3 + (size_t)Bn * Cc * 4096;
  float* out_o5 = out_o4 + (size_t)Bn * Cc * 1024;

  const int M = Bn * Ntok;  // 10752
  const int MB = M / 64;    // 168

  pe_kernel<<<1024, 256, 0, stream>>>(peb);
  flatten_kernel<<<1024, 256, 0, stream>>>(res3, res4, res5, lemb, x, xb);

  for (int l = 0; l < 6; l++) {
    addpe_kernel<<<672, 256, 0, stream>>>(x, peb, qb);
    gemm_mfma_b<0, 1><<<dim3(2, MB), 256, 0, stream>>>(
        xb, val_W + (size_t)l * 65536, val_b + l * 256, valueb, M, 256, 256);
    gemm_offaw<<<dim3(3, MB), 256, 0, stream>>>(
        qb, off_W + (size_t)l * 49152, off_b + l * 192,
        aw_W + (size_t)l * 24576, aw_b + l * 96, offb, awl, M);
    msda_sample<<<10752, 256, 0, stream>>>(valueb, offb, awl, attnb);
    gemm_mfma_b<0, 0><<<dim3(2, MB), 256, 0, stream>>>(
        attnb, out_W + (size_t)l * 65536, out_b + l * 256, tmp, M, 256, 256);
    ln_residual<<<M / 4, 256, 0, stream>>>(x, xb, tmp, ln1_g + l * 256,
                                           ln1_b + l * 256);
    gemm_mfma_b<1, 1><<<dim3(8, MB), 256, 0, stream>>>(
        xb, fc1_W + (size_t)l * 262144, fc1_b + l * 1024, hb, M, 1024, 256);
    gemm_mfma_b<0, 0><<<dim3(2, MB), 256, 0, stream>>>(
        hb, fc2_W + (size_t)l * 262144, fc2_b + l * 256, tmp, M, 256, 1024);
    ln_residual<<<M / 4, 256, 0, stream>>>(x, xb, tmp, ln2_g + l * 256,
                                           ln2_b + l * 256);
  }

  // token outputs (read x fp32) — must precede sbuf (aliases x) writes
  rows_to_nchw<<<dim3(128, 8, 2), dim3(32, 8), 0, stream>>>(x, out_o3, 0, 4096);
  rows_to_nchw<<<dim3(32, 8, 2), dim3(32, 8), 0, stream>>>(x, out_o4, 4096, 1024);
  rows_to_nchw<<<dim3(8, 8, 2), dim3(32, 8), 0, stream>>>(x, out_o5, 5120, 256);

  // FPN tail
  gemm_tn_mfma<<<dim3(2, 512), 256, 0, stream>>>(res2, lat_W, lat_b, tbuf);
  upsample_add<<<32768, 256, 0, stream>>>(x, tbuf);
  wt_transpose<<<1024, 256, 0, stream>>>(sm_W, wtbuf);
  conv3x3_mfma<<<dim3(2, 512), 256, 0, stream>>>(tbuf, wtbuf, sm_b, sbuf);
  gn_partial<<<1024, 256, 0, stream>>>(sbuf, gnpart);
  gn_final<<<1, 64, 0, stream>>>(gnpart, gnstat);
  gn_apply<<<dim3(512, 8, 2), dim3(32, 8), 0, stream>>>(sbuf, gnstat, gn_g,
                                                        gn_b, out_s);
}

// Round 5
// 1259.620 us; speedup vs baseline: 3.9085x; 1.1514x over previous
//
#include <hip/hip_runtime.h>

// ---------------- constants ----------------
namespace {
constexpr int Bn   = 2;
constexpr int Cc   = 256;
constexpr int Ntok = 5376;      // 4096 + 1024 + 256
constexpr int Ffn  = 1024;
constexpr int HW2  = 128 * 128; // res2 spatial
constexpr float EPSf = 1e-5f;
}

typedef __attribute__((ext_vector_type(8))) short bf16x8;
typedef __attribute__((ext_vector_type(4))) float f32x4;

__device__ inline unsigned short f2bf(float x) {
  unsigned u = __float_as_uint(x);
  return (unsigned short)((u + 0x7fffu + ((u >> 16) & 1u)) >> 16);
}
__device__ inline float bf2f(unsigned short b) {
  return __uint_as_float((unsigned)b << 16);
}

// store one 16B chunk (8 bf16) to LDS, XOR-swizzled granule
__device__ inline void store_chunk_f32(unsigned short* lds, int row, int g,
                                       const float* v8) {
  int sg = g ^ (row & 7);
  unsigned short tmp[8];
#pragma unroll
  for (int j = 0; j < 8; j++) tmp[j] = f2bf(v8[j]);
  *reinterpret_cast<uint4*>(&lds[row * 64 + sg * 8]) =
      *reinterpret_cast<const uint4*>(tmp);
}
__device__ inline void store_chunk_bf(unsigned short* lds, int row, int g,
                                      uint4 v) {
  int sg = g ^ (row & 7);
  *reinterpret_cast<uint4*>(&lds[row * 64 + sg * 8]) = v;
}

// ---------------- positional encoding (bf16 out) ----------------
__global__ void pe_kernel(unsigned short* __restrict__ pe) {
  for (int i = blockIdx.x * blockDim.x + threadIdx.x; i < Ntok * Cc;
       i += gridDim.x * blockDim.x) {
    int c = i & 255;
    int p = i >> 8;
    int li = (p < 4096) ? 0 : ((p < 5120) ? 1 : 2);
    int start = (li == 0) ? 0 : ((li == 1) ? 4096 : 5120);
    int W = 64 >> li;
    int sp = p - start;
    int shift = 6 - li;
    int iy = sp >> shift;
    int ix = sp & (W - 1);
    int j = c & 63;
    int sel = c >> 6;
    float div = expf(-(float)j * (9.210340371976184f / 64.f));
    float coord = (sel < 2) ? (float)iy : (float)ix;
    float arg = coord * div;
    pe[i] = f2bf((sel & 1) ? cosf(arg) : sinf(arg));
  }
}

// ---------------- flatten + level_embed -> x fp32 + xb bf16 ----------------
__global__ void flatten_kernel(const float* __restrict__ r3,
                               const float* __restrict__ r4,
                               const float* __restrict__ r5,
                               const float* __restrict__ lemb,
                               float* __restrict__ x,
                               unsigned short* __restrict__ xb) {
  for (int i = blockIdx.x * blockDim.x + threadIdx.x; i < Bn * Ntok * Cc;
       i += gridDim.x * blockDim.x) {
    int c = i & 255;
    int rest = i >> 8;
    int p = rest % Ntok;
    int b = rest / Ntok;
    int li = (p < 4096) ? 0 : ((p < 5120) ? 1 : 2);
    int start = (li == 0) ? 0 : ((li == 1) ? 4096 : 5120);
    int size = (li == 0) ? 4096 : ((li == 1) ? 1024 : 256);
    const float* f = (li == 0) ? r3 : ((li == 1) ? r4 : r5);
    int sp = p - start;
    float v = f[((size_t)(b * Cc + c)) * size + sp] + lemb[li * Cc + c];
    x[i] = v;
    xb[i] = f2bf(v);
  }
}

// ---------------- q = x + pe -> bf16 ----------------
__global__ void addpe_kernel(const float* __restrict__ x,
                             const unsigned short* __restrict__ pe,
                             unsigned short* __restrict__ qb) {
  const int NPC = Ntok * Cc;
  int n4 = Bn * NPC / 4;
  for (int i = blockIdx.x * blockDim.x + threadIdx.x; i < n4;
       i += gridDim.x * blockDim.x) {
    int e = i * 4;
    int pc = (e >= NPC) ? e - NPC : e;
    float4 xv = *reinterpret_cast<const float4*>(&x[e]);
    ushort4 pv = *reinterpret_cast<const ushort4*>(&pe[pc]);
    unsigned short t[4] = {f2bf(xv.x + bf2f(pv.x)), f2bf(xv.y + bf2f(pv.y)),
                           f2bf(xv.z + bf2f(pv.z)), f2bf(xv.w + bf2f(pv.w))};
    *reinterpret_cast<uint2*>(&qb[e]) = *reinterpret_cast<const uint2*>(t);
  }
}

// =================================================================
// MFMA GEMM: out(M,N) = A(M,K)bf16 @ W(N,K)^T fp32 + bias.
// BM=64, BN=128, BK=64, 256 threads = 4 waves (2x2), 16x16x32 mfma.
// =================================================================
template <int ACT, int OBF>
__global__ __launch_bounds__(256) void gemm_mfma_b(
    const unsigned short* __restrict__ A, const float* __restrict__ W,
    const float* __restrict__ bias, void* __restrict__ outp,
    int M, int N, int K) {
  __shared__ unsigned short As[64 * 64];
  __shared__ unsigned short Ws[128 * 64];
  const int tid = threadIdx.x;
  const int m0 = blockIdx.y * 64, n0 = blockIdx.x * 128;
  const int wid = tid >> 6, lane = tid & 63;
  const int wm = wid >> 1, wn = wid & 1;
  const int lr = lane & 15, lh = lane >> 4;
  f32x4 acc[2][4];
#pragma unroll
  for (int i = 0; i < 2; i++)
#pragma unroll
    for (int j = 0; j < 4; j++) acc[i][j] = f32x4{0.f, 0.f, 0.f, 0.f};

  for (int k0 = 0; k0 < K; k0 += 64) {
#pragma unroll
    for (int i = 0; i < 2; i++) {
      int c = tid + i * 256;
      int row = c >> 3, g = c & 7;
      uint4 v = *reinterpret_cast<const uint4*>(
          &A[(size_t)(m0 + row) * K + k0 + g * 8]);
      store_chunk_bf(As, row, g, v);
    }
#pragma unroll
    for (int i = 0; i < 4; i++) {
      int c = tid + i * 256;
      int row = c >> 3, g = c & 7;
      int n = n0 + row;
      float v8[8] = {0.f, 0.f, 0.f, 0.f, 0.f, 0.f, 0.f, 0.f};
      if (n < N) {
        const float4* src =
            reinterpret_cast<const float4*>(&W[(size_t)n * K + k0 + g * 8]);
        float4 v0 = src[0], v1 = src[1];
        v8[0] = v0.x; v8[1] = v0.y; v8[2] = v0.z; v8[3] = v0.w;
        v8[4] = v1.x; v8[5] = v1.y; v8[6] = v1.z; v8[7] = v1.w;
      }
      store_chunk_f32(Ws, row, g, v8);
    }
    __syncthreads();
    bf16x8 af[2][2], bfr[4][2];
#pragma unroll
    for (int mi = 0; mi < 2; mi++) {
      int r = wm * 32 + mi * 16 + lr;
#pragma unroll
      for (int s = 0; s < 2; s++) {
        int g = s * 4 + lh;
        af[mi][s] =
            *reinterpret_cast<const bf16x8*>(&As[r * 64 + (g ^ (r & 7)) * 8]);
      }
    }
#pragma unroll
    for (int nj = 0; nj < 4; nj++) {
      int r = wn * 64 + nj * 16 + lr;
#pragma unroll
      for (int s = 0; s < 2; s++) {
        int g = s * 4 + lh;
        bfr[nj][s] =
            *reinterpret_cast<const bf16x8*>(&Ws[r * 64 + (g ^ (r & 7)) * 8]);
      }
    }
#pragma unroll
    for (int mi = 0; mi < 2; mi++)
#pragma unroll
      for (int nj = 0; nj < 4; nj++) {
        acc[mi][nj] = __builtin_amdgcn_mfma_f32_16x16x32_bf16(
            af[mi][0], bfr[nj][0], acc[mi][nj], 0, 0, 0);
        acc[mi][nj] = __builtin_amdgcn_mfma_f32_16x16x32_bf16(
            af[mi][1], bfr[nj][1], acc[mi][nj], 0, 0, 0);
      }
    __syncthreads();
  }
#pragma unroll
  for (int mi = 0; mi < 2; mi++) {
    int row = m0 + wm * 32 + mi * 16 + lh * 4;
#pragma unroll
    for (int nj = 0; nj < 4; nj++) {
      int col = n0 + wn * 64 + nj * 16 + lr;
      if (col >= N) continue;
      float b = bias[col];
#pragma unroll
      for (int r = 0; r < 4; r++) {
        float v = acc[mi][nj][r] + b;
        if (ACT) v = fmaxf(v, 0.f);
        if (OBF)
          ((unsigned short*)outp)[(size_t)(row + r) * N + col] = f2bf(v);
        else
          ((float*)outp)[(size_t)(row + r) * N + col] = v;
      }
    }
  }
}

// -------- fused off(192)+aw(96) GEMM over qb: virtual N=288 --------
__global__ __launch_bounds__(256) void gemm_offaw(
    const unsigned short* __restrict__ A, const float* __restrict__ offW,
    const float* __restrict__ offB, const float* __restrict__ awW,
    const float* __restrict__ awB, float* __restrict__ offO,
    float* __restrict__ awO, int M) {
  __shared__ unsigned short As[64 * 64];
  __shared__ unsigned short Ws[128 * 64];
  const int tid = threadIdx.x;
  const int m0 = blockIdx.y * 64, n0 = blockIdx.x * 128;
  const int wid = tid >> 6, lane = tid & 63;
  const int wm = wid >> 1, wn = wid & 1;
  const int lr = lane & 15, lh = lane >> 4;
  f32x4 acc[2][4];
#pragma unroll
  for (int i = 0; i < 2; i++)
#pragma unroll
    for (int j = 0; j < 4; j++) acc[i][j] = f32x4{0.f, 0.f, 0.f, 0.f};

  for (int k0 = 0; k0 < 256; k0 += 64) {
#pragma unroll
    for (int i = 0; i < 2; i++) {
      int c = tid + i * 256;
      int row = c >> 3, g = c & 7;
      uint4 v = *reinterpret_cast<const uint4*>(
          &A[(size_t)(m0 + row) * 256 + k0 + g * 8]);
      store_chunk_bf(As, row, g, v);
    }
#pragma unroll
    for (int i = 0; i < 4; i++) {
      int c = tid + i * 256;
      int row = c >> 3, g = c & 7;
      int n = n0 + row;
      float v8[8] = {0.f, 0.f, 0.f, 0.f, 0.f, 0.f, 0.f, 0.f};
      const float* src = nullptr;
      if (n < 192) src = &offW[(size_t)n * 256 + k0 + g * 8];
      else if (n < 288) src = &awW[(size_t)(n - 192) * 256 + k0 + g * 8];
      if (src) {
        float4 v0 = reinterpret_cast<const float4*>(src)[0];
        float4 v1 = reinterpret_cast<const float4*>(src)[1];
        v8[0] = v0.x; v8[1] = v0.y; v8[2] = v0.z; v8[3] = v0.w;
        v8[4] = v1.x; v8[5] = v1.y; v8[6] = v1.z; v8[7] = v1.w;
      }
      store_chunk_f32(Ws, row, g, v8);
    }
    __syncthreads();
    bf16x8 af[2][2], bfr[4][2];
#pragma unroll
    for (int mi = 0; mi < 2; mi++) {
      int r = wm * 32 + mi * 16 + lr;
#pragma unroll
      for (int s = 0; s < 2; s++) {
        int g = s * 4 + lh;
        af[mi][s] =
            *reinterpret_cast<const bf16x8*>(&As[r * 64 + (g ^ (r & 7)) * 8]);
      }
    }
#pragma unroll
    for (int nj = 0; nj < 4; nj++) {
      int r = wn * 64 + nj * 16 + lr;
#pragma unroll
      for (int s = 0; s < 2; s++) {
        int g = s * 4 + lh;
        bfr[nj][s] =
            *reinterpret_cast<const bf16x8*>(&Ws[r * 64 + (g ^ (r & 7)) * 8]);
      }
    }
#pragma unroll
    for (int mi = 0; mi < 2; mi++)
#pragma unroll
      for (int nj = 0; nj < 4; nj++) {
        acc[mi][nj] = __builtin_amdgcn_mfma_f32_16x16x32_bf16(
            af[mi][0], bfr[nj][0], acc[mi][nj], 0, 0, 0);
        acc[mi][nj] = __builtin_amdgcn_mfma_f32_16x16x32_bf16(
            af[mi][1], bfr[nj][1], acc[mi][nj], 0, 0, 0);
      }
    __syncthreads();
  }
#pragma unroll
  for (int mi = 0; mi < 2; mi++) {
    int row = m0 + wm * 32 + mi * 16 + lh * 4;
#pragma unroll
    for (int nj = 0; nj < 4; nj++) {
      int col = n0 + wn * 64 + nj * 16 + lr;
      if (col >= 288) continue;
      float b = (col < 192) ? offB[col] : awB[col - 192];
#pragma unroll
      for (int r = 0; r < 4; r++) {
        float v = acc[mi][nj][r] + b;
        if (col < 192)
          offO[(size_t)(row + r) * 192 + col] = v;
        else
          awO[(size_t)(row + r) * 96 + col - 192] = v;
      }
    }
  }
}

// ------------- implicit-GEMM 3x3 conv, bf16 in, fp32 out -------------
__global__ __launch_bounds__(256) void conv3x3_mfma(
    const unsigned short* __restrict__ T, const unsigned short* __restrict__ Wt,
    const float* __restrict__ bias, float* __restrict__ out) {
  __shared__ unsigned short As[64 * 64];
  __shared__ unsigned short Ws[128 * 64];
  const int tid = threadIdx.x;
  const int m0 = blockIdx.y * 64, n0 = blockIdx.x * 128;
  const int b = m0 >> 14;
  const int p0 = m0 & 16383;
  const int y = p0 >> 7;
  const int x0 = p0 & 127;
  const int wid = tid >> 6, lane = tid & 63;
  const int wm = wid >> 1, wn = wid & 1;
  const int lr = lane & 15, lh = lane >> 4;
  f32x4 acc[2][4];
#pragma unroll
  for (int i = 0; i < 2; i++)
#pragma unroll
    for (int j = 0; j < 4; j++) acc[i][j] = f32x4{0.f, 0.f, 0.f, 0.f};

  for (int k0 = 0; k0 < 2304; k0 += 64) {
    int tap = k0 >> 8;
    int cb = k0 & 255;
    int dy = tap / 3 - 1, dx = tap % 3 - 1;
    int yy = y + dy;
#pragma unroll
    for (int i = 0; i < 2; i++) {
      int c = tid + i * 256;
      int row = c >> 3, g = c & 7;
      int xx = x0 + row + dx;
      uint4 v = uint4{0, 0, 0, 0};
      if (yy >= 0 && yy < 128 && xx >= 0 && xx < 128)
        v = *reinterpret_cast<const uint4*>(
            &T[((size_t)(b * 16384 + yy * 128 + xx)) * 256 + cb + g * 8]);
      store_chunk_bf(As, row, g, v);
    }
#pragma unroll
    for (int i = 0; i < 4; i++) {
      int c = tid + i * 256;
      int row = c >> 3, g = c & 7;
      uint4 v = *reinterpret_cast<const uint4*>(
          &Wt[(size_t)(n0 + row) * 2304 + k0 + g * 8]);
      store_chunk_bf(Ws, row, g, v);
    }
    __syncthreads();
    bf16x8 af[2][2], bfr[4][2];
#pragma unroll
    for (int mi = 0; mi < 2; mi++) {
      int r = wm * 32 + mi * 16 + lr;
#pragma unroll
      for (int s = 0; s < 2; s++) {
        int g = s * 4 + lh;
        af[mi][s] =
            *reinterpret_cast<const bf16x8*>(&As[r * 64 + (g ^ (r & 7)) * 8]);
      }
    }
#pragma unroll
    for (int nj = 0; nj < 4; nj++) {
      int r = wn * 64 + nj * 16 + lr;
#pragma unroll
      for (int s = 0; s < 2; s++) {
        int g = s * 4 + lh;
        bfr[nj][s] =
            *reinterpret_cast<const bf16x8*>(&Ws[r * 64 + (g ^ (r & 7)) * 8]);
      }
    }
#pragma unroll
    for (int mi = 0; mi < 2; mi++)
#pragma unroll
      for (int nj = 0; nj < 4; nj++) {
        acc[mi][nj] = __builtin_amdgcn_mfma_f32_16x16x32_bf16(
            af[mi][0], bfr[nj][0], acc[mi][nj], 0, 0, 0);
        acc[mi][nj] = __builtin_amdgcn_mfma_f32_16x16x32_bf16(
            af[mi][1], bfr[nj][1], acc[mi][nj], 0, 0, 0);
      }
    __syncthreads();
  }
#pragma unroll
  for (int mi = 0; mi < 2; mi++) {
    int row = m0 + wm * 32 + mi * 16 + lh * 4;
#pragma unroll
    for (int nj = 0; nj < 4; nj++) {
      int col = n0 + wn * 64 + nj * 16 + lr;
      float b = bias[col];
#pragma unroll
      for (int r = 0; r < 4; r++)
        out[(size_t)(row + r) * 256 + col] = acc[mi][nj][r] + b;
    }
  }
}

// ------------- TN GEMM (1x1 lateral conv): A=(B,256,HW) NCHW fp32, out bf16 -------------
__global__ __launch_bounds__(256) void gemm_tn_mfma(
    const float* __restrict__ A, const float* __restrict__ W,
    const float* __restrict__ bias, unsigned short* __restrict__ out) {
  __shared__ unsigned short As[64 * 64];
  __shared__ unsigned short Ws[128 * 64];
  const int tid = threadIdx.x;
  const int m0 = blockIdx.y * 64, n0 = blockIdx.x * 128;
  const int b = m0 >> 14;
  const int p0 = m0 & 16383;
  const int wid = tid >> 6, lane = tid & 63;
  const int wm = wid >> 1, wn = wid & 1;
  const int lr = lane & 15, lh = lane >> 4;
  f32x4 acc[2][4];
#pragma unroll
  for (int i = 0; i < 2; i++)
#pragma unroll
    for (int j = 0; j < 4; j++) acc[i][j] = f32x4{0.f, 0.f, 0.f, 0.f};

  for (int k0 = 0; k0 < 256; k0 += 64) {
#pragma unroll
    for (int i = 0; i < 2; i++) {
      int c = tid + i * 256;
      int row = c & 63, g = c >> 6;
      float v8[8];
#pragma unroll
      for (int j = 0; j < 8; j++)
        v8[j] = A[(size_t)(b * 256 + k0 + g * 8 + j) * 16384 + p0 + row];
      store_chunk_f32(As, row, g, v8);
    }
#pragma unroll
    for (int i = 0; i < 4; i++) {
      int c = tid + i * 256;
      int row = c >> 3, g = c & 7;
      const float4* src =
          reinterpret_cast<const float4*>(&W[(size_t)(n0 + row) * 256 + k0 + g * 8]);
      float4 v0 = src[0], v1 = src[1];
      float v8[8] = {v0.x, v0.y, v0.z, v0.w, v1.x, v1.y, v1.z, v1.w};
      store_chunk_f32(Ws, row, g, v8);
    }
    __syncthreads();
    bf16x8 af[2][2], bfr[4][2];
#pragma unroll
    for (int mi = 0; mi < 2; mi++) {
      int r = wm * 32 + mi * 16 + lr;
#pragma unroll
      for (int s = 0; s < 2; s++) {
        int g = s * 4 + lh;
        af[mi][s] =
            *reinterpret_cast<const bf16x8*>(&As[r * 64 + (g ^ (r & 7)) * 8]);
      }
    }
#pragma unroll
    for (int nj = 0; nj < 4; nj++) {
      int r = wn * 64 + nj * 16 + lr;
#pragma unroll
      for (int s = 0; s < 2; s++) {
        int g = s * 4 + lh;
        bfr[nj][s] =
            *reinterpret_cast<const bf16x8*>(&Ws[r * 64 + (g ^ (r & 7)) * 8]);
      }
    }
#pragma unroll
    for (int mi = 0; mi < 2; mi++)
#pragma unroll
      for (int nj = 0; nj < 4; nj++) {
        acc[mi][nj] = __builtin_amdgcn_mfma_f32_16x16x32_bf16(
            af[mi][0], bfr[nj][0], acc[mi][nj], 0, 0, 0);
        acc[mi][nj] = __builtin_amdgcn_mfma_f32_16x16x32_bf16(
            af[mi][1], bfr[nj][1], acc[mi][nj], 0, 0, 0);
      }
    __syncthreads();
  }
#pragma unroll
  for (int mi = 0; mi < 2; mi++) {
    int row = m0 + wm * 32 + mi * 16 + lh * 4;
#pragma unroll
    for (int nj = 0; nj < 4; nj++) {
      int col = n0 + wn * 64 + nj * 16 + lr;
      float b = bias[col];
#pragma unroll
      for (int r = 0; r < 4; r++)
        out[(size_t)(row + r) * 256 + col] = f2bf(acc[mi][nj][r] + b);
    }
  }
}

// ---------------- MSDA prep: one thread per (b,n,h) ----------------
// record per point: [int4 corner-elem-idx][float4 folded weights], 32B
__global__ __launch_bounds__(256) void msda_prep(
    const float* __restrict__ off, const float* __restrict__ awl,
    float* __restrict__ rec) {
  int gid = blockIdx.x * 256 + threadIdx.x;  // (b*Ntok+n)*8+h, 86016 total
  int h = gid & 7;
  int bn = gid >> 3;
  int n = bn % Ntok;
  int b = bn / Ntok;

  int li0 = (n < 4096) ? 0 : ((n < 5120) ? 1 : 2);
  int start0 = (li0 == 0) ? 0 : ((li0 == 1) ? 4096 : 5120);
  int shift = 6 - li0;
  int Wn = 1 << shift;
  int sp = n - start0;
  int iy = sp >> shift;
  int ix = sp & (Wn - 1);
  float refx = (ix + 0.5f) / (float)Wn;
  float refy = (iy + 0.5f) / (float)Wn;

  const float* ap = awl + (size_t)bn * 96 + h * 12;
  float lg[12];
  float mx = -1e30f;
#pragma unroll
  for (int j = 0; j < 12; j++) { lg[j] = ap[j]; mx = fmaxf(mx, lg[j]); }
  float ssum = 0.f;
#pragma unroll
  for (int j = 0; j < 12; j++) { lg[j] = expf(lg[j] - mx); ssum += lg[j]; }
  float inv = 1.f / ssum;

  const float* op = off + (size_t)bn * 192 + h * 24;
  float* rp = rec + (size_t)gid * 96;
#pragma unroll
  for (int p = 0; p < 12; p++) {
    int li = p >> 2;
    int HWl = 64 >> li;
    int st = (li == 0) ? 0 : ((li == 1) ? 4096 : 5120);
    float ox = op[p * 2 + 0];
    float oy = op[p * 2 + 1];
    float lx = refx + ox / (float)HWl;
    float ly = refy + oy / (float)HWl;
    float fx = lx * (float)HWl - 0.5f;
    float fy = ly * (float)HWl - 0.5f;
    float x0f = floorf(fx), y0f = floorf(fy);
    float wx = fx - x0f, wy = fy - y0f;
    int ix0 = (int)x0f, iy0 = (int)y0f;
    float w = lg[p] * inv;
    // corner validity, clamped index, folded weight
    int base = (b * Ntok + st) * 256 + h * 32;  // elem idx of (pos=0, c=0)
    int idx[4];
    float wgt[4];
#pragma unroll
    for (int cr = 0; cr < 4; cr++) {
      int cx = ix0 + (cr & 1);
      int cy = iy0 + (cr >> 1);
      bool valid = (cx >= 0) & (cx < HWl) & (cy >= 0) & (cy < HWl);
      float wc = ((cr & 1) ? wx : 1.f - wx) * ((cr >> 1) ? wy : 1.f - wy);
      int cxc = min(max(cx, 0), HWl - 1);
      int cyc = min(max(cy, 0), HWl - 1);
      idx[cr] = base + (cyc * HWl + cxc) * 256;
      wgt[cr] = valid ? (w * wc) : 0.f;
    }
    *reinterpret_cast<int4*>(rp + p * 8) = int4{idx[0], idx[1], idx[2], idx[3]};
    *reinterpret_cast<float4*>(rp + p * 8 + 4) =
        float4{wgt[0], wgt[1], wgt[2], wgt[3]};
  }
}

// ---------------- MSDA gather: 32-lane group per (b,n,h), lane=channel ----------------
__global__ __launch_bounds__(256) void msda_gather(
    const unsigned short* __restrict__ value, const float* __restrict__ rec,
    unsigned short* __restrict__ attn) {
  int gid = blockIdx.x * 8 + (threadIdx.x >> 5);
  int lane = threadIdx.x & 31;
  const float* rp = rec + (size_t)gid * 96;
  const unsigned short* vb = value + lane;
  float acc = 0.f;
#pragma unroll
  for (int p = 0; p < 12; p++) {
    int4 idx = *reinterpret_cast<const int4*>(rp + p * 8);
    float4 w = *reinterpret_cast<const float4*>(rp + p * 8 + 4);
    acc += w.x * bf2f(vb[idx.x]);
    acc += w.y * bf2f(vb[idx.y]);
    acc += w.z * bf2f(vb[idx.z]);
    acc += w.w * bf2f(vb[idx.w]);
  }
  attn[(size_t)gid * 32 + lane] = f2bf(acc);
}

// ---------------- residual add + LayerNorm, wave-per-row ----------------
// writes x fp32 (in place) and xb bf16
__global__ __launch_bounds__(256) void ln_residual(
    float* __restrict__ x, unsigned short* __restrict__ xb,
    const float* __restrict__ r, const float* __restrict__ g,
    const float* __restrict__ bta) {
  int w = threadIdx.x >> 6, lane = threadIdx.x & 63;
  int row = blockIdx.x * 4 + w;
  size_t base = (size_t)row * 256 + lane * 4;
  float4 v = *reinterpret_cast<const float4*>(&x[base]);
  float4 rr = *reinterpret_cast<const float4*>(&r[base]);
  v.x += rr.x; v.y += rr.y; v.z += rr.z; v.w += rr.w;
  float s = v.x + v.y + v.z + v.w;
#pragma unroll
  for (int o = 32; o > 0; o >>= 1) s += __shfl_xor(s, o);
  float mu = s * (1.f / 256.f);
  float4 d = {v.x - mu, v.y - mu, v.z - mu, v.w - mu};
  float sq = d.x * d.x + d.y * d.y + d.z * d.z + d.w * d.w;
#pragma unroll
  for (int o = 32; o > 0; o >>= 1) sq += __shfl_xor(sq, o);
  float rstd = rsqrtf(sq * (1.f / 256.f) + EPSf);
  float4 gv = *reinterpret_cast<const float4*>(&g[lane * 4]);
  float4 bv = *reinterpret_cast<const float4*>(&bta[lane * 4]);
  float4 o4 = {d.x * rstd * gv.x + bv.x, d.y * rstd * gv.y + bv.y,
               d.z * rstd * gv.z + bv.z, d.w * rstd * gv.w + bv.w};
  *reinterpret_cast<float4*>(&x[base]) = o4;
  unsigned short t[4] = {f2bf(o4.x), f2bf(o4.y), f2bf(o4.z), f2bf(o4.w)};
  *reinterpret_cast<uint2*>(&xb[base]) = *reinterpret_cast<const uint2*>(t);
}

// ---------------- bilinear 64->128 upsample, += into bf16 t ----------------
__global__ __launch_bounds__(256) void upsample_add(
    const float* __restrict__ xrows, unsigned short* __restrict__ t) {
  int bp = blockIdx.x;
  int c = threadIdx.x;
  int b = bp >> 14;
  int p = bp & 16383;
  int Y = p >> 7, X = p & 127;
  float yc = Y * 0.5f - 0.25f;
  float y0f = floorf(yc);
  float wy = yc - y0f;
  int y0 = (int)y0f, y1 = y0 + 1;
  int y0c = min(max(y0, 0), 63), y1c = min(max(y1, 0), 63);
  float xc = X * 0.5f - 0.25f;
  float x0f = floorf(xc);
  float wx = xc - x0f;
  int xq0 = (int)x0f, xq1 = xq0 + 1;
  int x0c = min(max(xq0, 0), 63), x1c = min(max(xq1, 0), 63);
  const float* base = xrows + (size_t)b * Ntok * 256;
  float v00 = base[(size_t)(y0c * 64 + x0c) * 256 + c];
  float v01 = base[(size_t)(y0c * 64 + x1c) * 256 + c];
  float v10 = base[(size_t)(y1c * 64 + x0c) * 256 + c];
  float v11 = base[(size_t)(y1c * 64 + x1c) * 256 + c];
  float v = (1.f - wy) * ((1.f - wx) * v00 + wx * v01) +
            wy * ((1.f - wx) * v10 + wx * v11);
  size_t idx = (size_t)bp * 256 + c;
  t[idx] = f2bf(bf2f(t[idx]) + v);
}

// ---------------- token rows -> NCHW output (tiled transpose) ----------------
__global__ void rows_to_nchw(const float* __restrict__ xrows,
                             float* __restrict__ out, int start, int size) {
  __shared__ float tile[32][33];
  int p0 = blockIdx.x * 32, c0 = blockIdx.y * 32, b = blockIdx.z;
  int tx = threadIdx.x, tyy = threadIdx.y;
  for (int i = tyy; i < 32; i += 8)
    tile[i][tx] = xrows[((size_t)(b * Ntok + start + p0 + i)) * 256 + c0 + tx];
  __syncthreads();
  for (int i = tyy; i < 32; i += 8)
    out[((size_t)(b * 256 + c0 + i)) * size + p0 + tx] = tile[tx][i];
}

// ---------------- conv weight repack (O,C,3,3) -> bf16 (O, tap*256+c) ----------------
__global__ void wt_transpose(const float* __restrict__ w,
                             unsigned short* __restrict__ wt) {
  for (int i = blockIdx.x * blockDim.x + threadIdx.x; i < 256 * 2304;
       i += gridDim.x * blockDim.x) {
    int o = i / 2304;
    int r = i % 2304;
    int tap = r >> 8;
    int c = r & 255;
    wt[i] = f2bf(w[((size_t)(o * 256 + c)) * 9 + tap]);
  }
}

// ---------------- GroupNorm partial sums ----------------
__global__ __launch_bounds__(256) void gn_partial(
    const float* __restrict__ s, float* __restrict__ part) {
  int blk = blockIdx.x;
  int pr = blk & 15;
  int bg = blk >> 4;
  int g = bg & 31;
  int b = bg >> 5;
  int tid = threadIdx.x;
  float sum = 0.f, sq = 0.f;
  for (int e = pr * 8192 + tid; e < (pr + 1) * 8192; e += 256) {
    int p = e >> 3, cc = e & 7;
    float v = s[((size_t)(b * 16384 + p)) * 256 + g * 8 + cc];
    sum += v;
    sq += v * v;
  }
  __shared__ float rs[256], rq[256];
  rs[tid] = sum;
  rq[tid] = sq;
  __syncthreads();
  for (int st = 128; st > 0; st >>= 1) {
    if (tid < st) { rs[tid] += rs[tid + st]; rq[tid] += rq[tid + st]; }
    __syncthreads();
  }
  if (tid == 0) {
    part[(size_t)blk * 2 + 0] = rs[0];
    part[(size_t)blk * 2 + 1] = rq[0];
  }
}

__global__ void gn_final(const float* __restrict__ part,
                         float* __restrict__ stats) {
  int tid = threadIdx.x;
  if (tid < 64) {
    float s = 0.f, q = 0.f;
    for (int j = 0; j < 16; j++) {
      s += part[(size_t)(tid * 16 + j) * 2 + 0];
      q += part[(size_t)(tid * 16 + j) * 2 + 1];
    }
    float mu = s * (1.f / 131072.f);
    float var = q * (1.f / 131072.f) - mu * mu;
    stats[tid * 2 + 0] = mu;
    stats[tid * 2 + 1] = rsqrtf(var + EPSf);
  }
}

// ---------------- GN apply + GELU + transpose to NCHW ----------------
__global__ void gn_apply(const float* __restrict__ s,
                         const float* __restrict__ stats,
                         const float* __restrict__ gg,
                         const float* __restrict__ gb,
                         float* __restrict__ out) {
  __shared__ float tile[32][33];
  int p0 = blockIdx.x * 32, c0 = blockIdx.y * 32, b = blockIdx.z;
  int tx = threadIdx.x, tyy = threadIdx.y;
  int c = c0 + tx;
  float mu = stats[(b * 32 + (c >> 3)) * 2 + 0];
  float rstd = stats[(b * 32 + (c >> 3)) * 2 + 1];
  float gw = gg[c], bw = gb[c];
  for (int i = tyy; i < 32; i += 8) {
    float v = s[((size_t)(b * 16384 + p0 + i)) * 256 + c];
    v = (v - mu) * rstd * gw + bw;
    v = 0.5f * v * (1.f + erff(v * 0.70710678118654752f));
    tile[i][tx] = v;
  }
  __syncthreads();
  for (int i = tyy; i < 32; i += 8)
    out[((size_t)(b * 256 + c0 + i)) * 16384 + p0 + tx] = tile[tx][i];
}

// ---------------- launcher ----------------
extern "C" void kernel_launch(void* const* d_in, const int* in_sizes, int n_in,
                              void* d_out, int out_size, void* d_ws,
                              size_t ws_size, hipStream_t stream) {
  (void)in_sizes; (void)n_in; (void)out_size; (void)ws_size;
  const float* res2  = (const float*)d_in[0];
  const float* res3  = (const float*)d_in[1];
  const float* res4  = (const float*)d_in[2];
  const float* res5  = (const float*)d_in[3];
  const float* lemb  = (const float*)d_in[4];
  const float* off_W = (const float*)d_in[5];
  const float* off_b = (const float*)d_in[6];
  const float* aw_W  = (const float*)d_in[7];
  const float* aw_b  = (const float*)d_in[8];
  const float* val_W = (const float*)d_in[9];
  const float* val_b = (const float*)d_in[10];
  const float* out_W = (const float*)d_in[11];
  const float* out_b = (const float*)d_in[12];
  const float* ln1_g = (const float*)d_in[13];
  const float* ln1_b = (const float*)d_in[14];
  const float* fc1_W = (const float*)d_in[15];
  const float* fc1_b = (const float*)d_in[16];
  const float* fc2_W = (const float*)d_in[17];
  const float* fc2_b = (const float*)d_in[18];
  const float* ln2_g = (const float*)d_in[19];
  const float* ln2_b = (const float*)d_in[20];
  const float* lat_W = (const float*)d_in[21];
  const float* lat_b = (const float*)d_in[22];
  const float* sm_W  = (const float*)d_in[23];
  const float* sm_b  = (const float*)d_in[24];
  const float* gn_g  = (const float*)d_in[25];
  const float* gn_b  = (const float*)d_in[26];

  float* ws = (float*)d_ws;
  const size_t BNC = (size_t)Bn * Ntok * Cc;  // 2752512
  // layout (float units); bf16 buffers take count/2 floats
  float*          x      = ws;                               // 0       (2752512)
  unsigned short* xb     = (unsigned short*)(ws + 2752512);  //         (1376256)
  unsigned short* peb    = (unsigned short*)(ws + 4128768);  //         (688128)
  unsigned short* qb     = (unsigned short*)(ws + 4816896);  //         (1376256)
  unsigned short* valueb = (unsigned short*)(ws + 6193152);  //         (1376256)
  float*          offb   = ws + 7569408;                     //         (2064384)
  float*          awl    = ws + 9633792;                     //         (1032192)
  unsigned short* attnb  = (unsigned short*)(ws + 10665984); //         (1376256)
  float*          tmp    = ws + 12042240;                    //         (2752512)
  unsigned short* hb     = (unsigned short*)(ws + 14794752); //         (5505024)
  unsigned short* tbuf   = hb;  // conv input aliases hb (dead after layers)
  unsigned short* wtbuf  = (unsigned short*)(ws + 20299776); //         (294912)
  float*          gnpart = ws + 20594688;                    //         (2048)
  float*          gnstat = ws + 20596736;                    //         (128)
  // total 20596864 floats = 82.4 MB
  // rec: 86016 groups * 12 pts * 8 words = 8257536 floats; live only between
  // prep and gather -> aliases tmp (12042240..14794752) + hb (..20299776),
  // both dead in that window. tmp+hb span = 8257536 floats exactly.
  float*          rec    = tmp;
  float*          sbuf   = ws;  // conv out fp32 (8388608 f): spans dead
                                // x..valueb + first part of dead offb

  float* out_s  = (float*)d_out;
  float* out_o3 = out_s + (size_t)Bn * Cc * HW2;
  float* out_o4 = out_o3 + (size_t)Bn * Cc * 4096;
  float* out_o5 = out_o4 + (size_t)Bn * Cc * 1024;

  const int M = Bn * Ntok;  // 10752
  const int MB = M / 64;    // 168

  pe_kernel<<<1024, 256, 0, stream>>>(peb);
  flatten_kernel<<<1024, 256, 0, stream>>>(res3, res4, res5, lemb, x, xb);

  for (int l = 0; l < 6; l++) {
    addpe_kernel<<<672, 256, 0, stream>>>(x, peb, qb);
    gemm_mfma_b<0, 1><<<dim3(2, MB), 256, 0, stream>>>(
        xb, val_W + (size_t)l * 65536, val_b + l * 256, valueb, M, 256, 256);
    gemm_offaw<<<dim3(3, MB), 256, 0, stream>>>(
        qb, off_W + (size_t)l * 49152, off_b + l * 192,
        aw_W + (size_t)l * 24576, aw_b + l * 96, offb, awl, M);
    msda_prep<<<336, 256, 0, stream>>>(offb, awl, rec);
    msda_gather<<<10752, 256, 0, stream>>>(valueb, rec, attnb);
    gemm_mfma_b<0, 0><<<dim3(2, MB), 256, 0, stream>>>(
        attnb, out_W + (size_t)l * 65536, out_b + l * 256, tmp, M, 256, 256);
    ln_residual<<<M / 4, 256, 0, stream>>>(x, xb, tmp, ln1_g + l * 256,
                                           ln1_b + l * 256);
    gemm_mfma_b<1, 1><<<dim3(8, MB), 256, 0, stream>>>(
        xb, fc1_W + (size_t)l * 262144, fc1_b + l * 1024, hb, M, 1024, 256);
    gemm_mfma_b<0, 0><<<dim3(2, MB), 256, 0, stream>>>(
        hb, fc2_W + (size_t)l * 262144, fc2_b + l * 256, tmp, M, 256, 1024);
    ln_residual<<<M / 4, 256, 0, stream>>>(x, xb, tmp, ln2_g + l * 256,
                                           ln2_b + l * 256);
  }

  // token outputs (read x fp32) — must precede sbuf (aliases x) writes
  rows_to_nchw<<<dim3(128, 8, 2), dim3(32, 8), 0, stream>>>(x, out_o3, 0, 4096);
  rows_to_nchw<<<dim3(32, 8, 2), dim3(32, 8), 0, stream>>>(x, out_o4, 4096, 1024);
  rows_to_nchw<<<dim3(8, 8, 2), dim3(32, 8), 0, stream>>>(x, out_o5, 5120, 256);

  // FPN tail
  gemm_tn_mfma<<<dim3(2, 512), 256, 0, stream>>>(res2, lat_W, lat_b, tbuf);
  upsample_add<<<32768, 256, 0, stream>>>(x, tbuf);
  wt_transpose<<<1024, 256, 0, stream>>>(sm_W, wtbuf);
  conv3x3_mfma<<<dim3(2, 512), 256, 0, stream>>>(tbuf, wtbuf, sm_b, sbuf);
  gn_partial<<<1024, 256, 0, stream>>>(sbuf, gnpart);
  gn_final<<<1, 64, 0, stream>>>(gnpart, gnstat);
  gn_apply<<<dim3(512, 8, 2), dim3(32, 8), 0, stream>>>(sbuf, gnstat, gn_g,
                                                        gn_b, out_s);
}

// Round 8
// 998.528 us; speedup vs baseline: 4.9304x; 1.2615x over previous
//
#include <hip/hip_runtime.h>

// ---------------- constants ----------------
namespace {
constexpr int Bn   = 2;
constexpr int Cc   = 256;
constexpr int Ntok = 5376;      // 4096 + 1024 + 256
constexpr int Ffn  = 1024;
constexpr int HW2  = 128 * 128; // res2 spatial
constexpr float EPSf = 1e-5f;
}

typedef __attribute__((ext_vector_type(8))) short bf16x8;
typedef __attribute__((ext_vector_type(4))) float f32x4;

__device__ inline unsigned short f2bf(float x) {
  unsigned u = __float_as_uint(x);
  return (unsigned short)((u + 0x7fffu + ((u >> 16) & 1u)) >> 16);
}
__device__ inline float bf2f(unsigned short b) {
  return __uint_as_float((unsigned)b << 16);
}

// store one 16B chunk (8 bf16) to LDS, XOR-swizzled granule
__device__ inline void store_chunk_f32(unsigned short* lds, int row, int g,
                                       const float* v8) {
  int sg = g ^ (row & 7);
  unsigned short tmp[8];
#pragma unroll
  for (int j = 0; j < 8; j++) tmp[j] = f2bf(v8[j]);
  *reinterpret_cast<uint4*>(&lds[row * 64 + sg * 8]) =
      *reinterpret_cast<const uint4*>(tmp);
}
__device__ inline void store_chunk_bf(unsigned short* lds, int row, int g,
                                      uint4 v) {
  int sg = g ^ (row & 7);
  *reinterpret_cast<uint4*>(&lds[row * 64 + sg * 8]) = v;
}

// ---------------- weight pre-convert: one layer -> bf16 block ----------------
// wbf layout (elems): val[65536] offaw[73728] out[65536] fc1[262144] fc2[262144]
__global__ __launch_bounds__(256) void wconv_layer(
    const float* __restrict__ valW, const float* __restrict__ offW,
    const float* __restrict__ awW, const float* __restrict__ outW,
    const float* __restrict__ fc1W, const float* __restrict__ fc2W,
    unsigned short* __restrict__ wbf) {
  int i4 = blockIdx.x * 256 + threadIdx.x;  // 182272 total
  if (i4 >= 182272) return;
  int e = i4 * 4;
  const float* src;
  int off;
  if (e < 65536) { src = valW; off = e; }
  else if (e < 139264) {
    int j = e - 65536;
    if (j < 49152) { src = offW; off = j; }
    else { src = awW; off = j - 49152; }
  } else if (e < 204800) { src = outW; off = e - 139264; }
  else if (e < 466944) { src = fc1W; off = e - 204800; }
  else { src = fc2W; off = e - 466944; }
  float4 v = *reinterpret_cast<const float4*>(&src[off]);
  unsigned short t[4] = {f2bf(v.x), f2bf(v.y), f2bf(v.z), f2bf(v.w)};
  *reinterpret_cast<uint2*>(&wbf[e]) = *reinterpret_cast<const uint2*>(t);
}

__global__ void wconv_flat(const float* __restrict__ src,
                           unsigned short* __restrict__ dst, int n4) {
  int i = blockIdx.x * 256 + threadIdx.x;
  if (i >= n4) return;
  float4 v = *reinterpret_cast<const float4*>(&src[i * 4]);
  unsigned short t[4] = {f2bf(v.x), f2bf(v.y), f2bf(v.z), f2bf(v.w)};
  *reinterpret_cast<uint2*>(&dst[i * 4]) = *reinterpret_cast<const uint2*>(t);
}

// ---------------- positional encoding (bf16 out) ----------------
__global__ void pe_kernel(unsigned short* __restrict__ pe) {
  for (int i = blockIdx.x * blockDim.x + threadIdx.x; i < Ntok * Cc;
       i += gridDim.x * blockDim.x) {
    int c = i & 255;
    int p = i >> 8;
    int li = (p < 4096) ? 0 : ((p < 5120) ? 1 : 2);
    int start = (li == 0) ? 0 : ((li == 1) ? 4096 : 5120);
    int W = 64 >> li;
    int sp = p - start;
    int shift = 6 - li;
    int iy = sp >> shift;
    int ix = sp & (W - 1);
    int j = c & 63;
    int sel = c >> 6;
    float div = expf(-(float)j * (9.210340371976184f / 64.f));
    float coord = (sel < 2) ? (float)iy : (float)ix;
    float arg = coord * div;
    pe[i] = f2bf((sel & 1) ? cosf(arg) : sinf(arg));
  }
}

// ---------------- flatten + level_embed -> x fp32, xb bf16, qb bf16 ----------------
__global__ void flatten_kernel(const float* __restrict__ r3,
                               const float* __restrict__ r4,
                               const float* __restrict__ r5,
                               const float* __restrict__ lemb,
                               const unsigned short* __restrict__ peb,
                               float* __restrict__ x,
                               unsigned short* __restrict__ xb,
                               unsigned short* __restrict__ qb) {
  const int NPC = Ntok * Cc;
  for (int i = blockIdx.x * blockDim.x + threadIdx.x; i < Bn * NPC;
       i += gridDim.x * blockDim.x) {
    int c = i & 255;
    int rest = i >> 8;
    int p = rest % Ntok;
    int b = rest / Ntok;
    int li = (p < 4096) ? 0 : ((p < 5120) ? 1 : 2);
    int start = (li == 0) ? 0 : ((li == 1) ? 4096 : 5120);
    int size = (li == 0) ? 4096 : ((li == 1) ? 1024 : 256);
    const float* f = (li == 0) ? r3 : ((li == 1) ? r4 : r5);
    int sp = p - start;
    float v = f[((size_t)(b * Cc + c)) * size + sp] + lemb[li * Cc + c];
    x[i] = v;
    xb[i] = f2bf(v);
    qb[i] = f2bf(v + bf2f(peb[i - b * NPC]));
  }
}

// =================================================================
// MFMA GEMM: out(M,N) = A(M,K)bf16 @ Wb(N,K)^T bf16 + bias.
// BM=64, BN=128, BK=64, 256 threads = 4 waves (2x2), 16x16x32 mfma.
// 1D grid (XCD-swizzled), register-prefetch double-buffering.
// =================================================================
template <int ACT, int OBF>
__global__ __launch_bounds__(256) void gemm_mfma_b(
    const unsigned short* __restrict__ A, const unsigned short* __restrict__ Wb,
    const float* __restrict__ bias, void* __restrict__ outp,
    int M, int N, int K, int nbx) {
  __shared__ unsigned short As[64 * 64];
  __shared__ unsigned short Ws[128 * 64];
  const int tid = threadIdx.x;
  const int nwg = gridDim.x;
  const int swz = (blockIdx.x & 7) * (nwg >> 3) + (blockIdx.x >> 3);
  const int m0 = (swz / nbx) * 64, n0 = (swz % nbx) * 128;
  const int wid = tid >> 6, lane = tid & 63;
  const int wm = wid >> 1, wn = wid & 1;
  const int lr = lane & 15, lh = lane >> 4;
  const int r8 = tid >> 3, g8 = tid & 7;
  f32x4 acc[2][4];
#pragma unroll
  for (int i = 0; i < 2; i++)
#pragma unroll
    for (int j = 0; j < 4; j++) acc[i][j] = f32x4{0.f, 0.f, 0.f, 0.f};

  uint4 ra[2], rw[4];
  const uint4 z4 = uint4{0, 0, 0, 0};
  // prologue loads (k=0)
#pragma unroll
  for (int i = 0; i < 2; i++)
    ra[i] = *reinterpret_cast<const uint4*>(
        &A[(size_t)(m0 + r8 + i * 32) * K + g8 * 8]);
#pragma unroll
  for (int i = 0; i < 4; i++) {
    int n = n0 + r8 + i * 32;
    rw[i] = (n < N) ? *reinterpret_cast<const uint4*>(
                          &Wb[(size_t)n * K + g8 * 8])
                    : z4;
  }

  for (int k0 = 0; k0 < K; k0 += 64) {
    if (k0) __syncthreads();
#pragma unroll
    for (int i = 0; i < 2; i++) store_chunk_bf(As, r8 + i * 32, g8, ra[i]);
#pragma unroll
    for (int i = 0; i < 4; i++) store_chunk_bf(Ws, r8 + i * 32, g8, rw[i]);
    __syncthreads();
    int kn = k0 + 64;
    if (kn < K) {
#pragma unroll
      for (int i = 0; i < 2; i++)
        ra[i] = *reinterpret_cast<const uint4*>(
            &A[(size_t)(m0 + r8 + i * 32) * K + kn + g8 * 8]);
#pragma unroll
      for (int i = 0; i < 4; i++) {
        int n = n0 + r8 + i * 32;
        rw[i] = (n < N) ? *reinterpret_cast<const uint4*>(
                              &Wb[(size_t)n * K + kn + g8 * 8])
                        : z4;
      }
    }
    bf16x8 af[2][2], bfr[4][2];
#pragma unroll
    for (int mi = 0; mi < 2; mi++) {
      int r = wm * 32 + mi * 16 + lr;
#pragma unroll
      for (int s = 0; s < 2; s++) {
        int g = s * 4 + lh;
        af[mi][s] =
            *reinterpret_cast<const bf16x8*>(&As[r * 64 + (g ^ (r & 7)) * 8]);
      }
    }
#pragma unroll
    for (int nj = 0; nj < 4; nj++) {
      int r = wn * 64 + nj * 16 + lr;
#pragma unroll
      for (int s = 0; s < 2; s++) {
        int g = s * 4 + lh;
        bfr[nj][s] =
            *reinterpret_cast<const bf16x8*>(&Ws[r * 64 + (g ^ (r & 7)) * 8]);
      }
    }
#pragma unroll
    for (int mi = 0; mi < 2; mi++)
#pragma unroll
      for (int nj = 0; nj < 4; nj++) {
        acc[mi][nj] = __builtin_amdgcn_mfma_f32_16x16x32_bf16(
            af[mi][0], bfr[nj][0], acc[mi][nj], 0, 0, 0);
        acc[mi][nj] = __builtin_amdgcn_mfma_f32_16x16x32_bf16(
            af[mi][1], bfr[nj][1], acc[mi][nj], 0, 0, 0);
      }
  }
#pragma unroll
  for (int mi = 0; mi < 2; mi++) {
    int row = m0 + wm * 32 + mi * 16 + lh * 4;
#pragma unroll
    for (int nj = 0; nj < 4; nj++) {
      int col = n0 + wn * 64 + nj * 16 + lr;
      if (col >= N) continue;
      float b = bias[col];
#pragma unroll
      for (int r = 0; r < 4; r++) {
        float v = acc[mi][nj][r] + b;
        if (ACT) v = fmaxf(v, 0.f);
        if (OBF)
          ((unsigned short*)outp)[(size_t)(row + r) * N + col] = f2bf(v);
        else
          ((float*)outp)[(size_t)(row + r) * N + col] = v;
      }
    }
  }
}

// -------- fused off(192)+aw(96) GEMM over qb: concat W (288,256) bf16 --------
__global__ __launch_bounds__(256) void gemm_offaw(
    const unsigned short* __restrict__ A, const unsigned short* __restrict__ Wb,
    const float* __restrict__ offB, const float* __restrict__ awB,
    float* __restrict__ offO, float* __restrict__ awO, int M) {
  __shared__ unsigned short As[64 * 64];
  __shared__ unsigned short Ws[128 * 64];
  const int tid = threadIdx.x;
  const int nwg = gridDim.x;
  const int swz = (blockIdx.x & 7) * (nwg >> 3) + (blockIdx.x >> 3);
  const int m0 = (swz / 3) * 64, n0 = (swz % 3) * 128;
  const int wid = tid >> 6, lane = tid & 63;
  const int wm = wid >> 1, wn = wid & 1;
  const int lr = lane & 15, lh = lane >> 4;
  const int r8 = tid >> 3, g8 = tid & 7;
  f32x4 acc[2][4];
#pragma unroll
  for (int i = 0; i < 2; i++)
#pragma unroll
    for (int j = 0; j < 4; j++) acc[i][j] = f32x4{0.f, 0.f, 0.f, 0.f};

  uint4 ra[2], rw[4];
  const uint4 z4 = uint4{0, 0, 0, 0};
#pragma unroll
  for (int i = 0; i < 2; i++)
    ra[i] = *reinterpret_cast<const uint4*>(
        &A[(size_t)(m0 + r8 + i * 32) * 256 + g8 * 8]);
#pragma unroll
  for (int i = 0; i < 4; i++) {
    int n = n0 + r8 + i * 32;
    rw[i] = (n < 288) ? *reinterpret_cast<const uint4*>(
                            &Wb[(size_t)n * 256 + g8 * 8])
                      : z4;
  }

  for (int k0 = 0; k0 < 256; k0 += 64) {
    if (k0) __syncthreads();
#pragma unroll
    for (int i = 0; i < 2; i++) store_chunk_bf(As, r8 + i * 32, g8, ra[i]);
#pragma unroll
    for (int i = 0; i < 4; i++) store_chunk_bf(Ws, r8 + i * 32, g8, rw[i]);
    __syncthreads();
    int kn = k0 + 64;
    if (kn < 256) {
#pragma unroll
      for (int i = 0; i < 2; i++)
        ra[i] = *reinterpret_cast<const uint4*>(
            &A[(size_t)(m0 + r8 + i * 32) * 256 + kn + g8 * 8]);
#pragma unroll
      for (int i = 0; i < 4; i++) {
        int n = n0 + r8 + i * 32;
        rw[i] = (n < 288) ? *reinterpret_cast<const uint4*>(
                                &Wb[(size_t)n * 256 + kn + g8 * 8])
                          : z4;
      }
    }
    bf16x8 af[2][2], bfr[4][2];
#pragma unroll
    for (int mi = 0; mi < 2; mi++) {
      int r = wm * 32 + mi * 16 + lr;
#pragma unroll
      for (int s = 0; s < 2; s++) {
        int g = s * 4 + lh;
        af[mi][s] =
            *reinterpret_cast<const bf16x8*>(&As[r * 64 + (g ^ (r & 7)) * 8]);
      }
    }
#pragma unroll
    for (int nj = 0; nj < 4; nj++) {
      int r = wn * 64 + nj * 16 + lr;
#pragma unroll
      for (int s = 0; s < 2; s++) {
        int g = s * 4 + lh;
        bfr[nj][s] =
            *reinterpret_cast<const bf16x8*>(&Ws[r * 64 + (g ^ (r & 7)) * 8]);
      }
    }
#pragma unroll
    for (int mi = 0; mi < 2; mi++)
#pragma unroll
      for (int nj = 0; nj < 4; nj++) {
        acc[mi][nj] = __builtin_amdgcn_mfma_f32_16x16x32_bf16(
            af[mi][0], bfr[nj][0], acc[mi][nj], 0, 0, 0);
        acc[mi][nj] = __builtin_amdgcn_mfma_f32_16x16x32_bf16(
            af[mi][1], bfr[nj][1], acc[mi][nj], 0, 0, 0);
      }
  }
#pragma unroll
  for (int mi = 0; mi < 2; mi++) {
    int row = m0 + wm * 32 + mi * 16 + lh * 4;
#pragma unroll
    for (int nj = 0; nj < 4; nj++) {
      int col = n0 + wn * 64 + nj * 16 + lr;
      if (col >= 288) continue;
      float b = (col < 192) ? offB[col] : awB[col - 192];
#pragma unroll
      for (int r = 0; r < 4; r++) {
        float v = acc[mi][nj][r] + b;
        if (col < 192)
          offO[(size_t)(row + r) * 192 + col] = v;
        else
          awO[(size_t)(row + r) * 96 + col - 192] = v;
      }
    }
  }
}

// ------------- implicit-GEMM 3x3 conv, bf16 in, fp32 out -------------
__global__ __launch_bounds__(256) void conv3x3_mfma(
    const unsigned short* __restrict__ T, const unsigned short* __restrict__ Wt,
    const float* __restrict__ bias, float* __restrict__ out) {
  __shared__ unsigned short As[64 * 64];
  __shared__ unsigned short Ws[128 * 64];
  const int tid = threadIdx.x;
  const int nwg = gridDim.x;  // 1024
  const int swz = (blockIdx.x & 7) * (nwg >> 3) + (blockIdx.x >> 3);
  const int m0 = (swz >> 1) * 64, n0 = (swz & 1) * 128;
  const int b = m0 >> 14;
  const int p0 = m0 & 16383;
  const int y = p0 >> 7;
  const int x0 = p0 & 127;
  const int wid = tid >> 6, lane = tid & 63;
  const int wm = wid >> 1, wn = wid & 1;
  const int lr = lane & 15, lh = lane >> 4;
  const int r8 = tid >> 3, g8 = tid & 7;
  f32x4 acc[2][4];
#pragma unroll
  for (int i = 0; i < 2; i++)
#pragma unroll
    for (int j = 0; j < 4; j++) acc[i][j] = f32x4{0.f, 0.f, 0.f, 0.f};

  uint4 ra[2], rw[4];
  auto loadA = [&](int kc, uint4* r) {
    int tap = kc >> 2;
    int cb = (kc & 3) * 64;
    int dy = tap / 3 - 1, dx = tap % 3 - 1;
    int yy = y + dy;
#pragma unroll
    for (int i = 0; i < 2; i++) {
      int row = r8 + i * 32;
      int xx = x0 + row + dx;
      uint4 v = uint4{0, 0, 0, 0};
      if (yy >= 0 && yy < 128 && xx >= 0 && xx < 128)
        v = *reinterpret_cast<const uint4*>(
            &T[((size_t)(b * 16384 + yy * 128 + xx)) * 256 + cb + g8 * 8]);
      r[i] = v;
    }
  };
  auto loadW = [&](int kc, uint4* r) {
#pragma unroll
    for (int i = 0; i < 4; i++)
      r[i] = *reinterpret_cast<const uint4*>(
          &Wt[(size_t)(n0 + r8 + i * 32) * 2304 + kc * 64 + g8 * 8]);
  };
  loadA(0, ra);
  loadW(0, rw);

  for (int kc = 0; kc < 36; kc++) {
    if (kc) __syncthreads();
#pragma unroll
    for (int i = 0; i < 2; i++) store_chunk_bf(As, r8 + i * 32, g8, ra[i]);
#pragma unroll
    for (int i = 0; i < 4; i++) store_chunk_bf(Ws, r8 + i * 32, g8, rw[i]);
    __syncthreads();
    if (kc + 1 < 36) {
      loadA(kc + 1, ra);
      loadW(kc + 1, rw);
    }
    bf16x8 af[2][2], bfr[4][2];
#pragma unroll
    for (int mi = 0; mi < 2; mi++) {
      int r = wm * 32 + mi * 16 + lr;
#pragma unroll
      for (int s = 0; s < 2; s++) {
        int g = s * 4 + lh;
        af[mi][s] =
            *reinterpret_cast<const bf16x8*>(&As[r * 64 + (g ^ (r & 7)) * 8]);
      }
    }
#pragma unroll
    for (int nj = 0; nj < 4; nj++) {
      int r = wn * 64 + nj * 16 + lr;
#pragma unroll
      for (int s = 0; s < 2; s++) {
        int g = s * 4 + lh;
        bfr[nj][s] =
            *reinterpret_cast<const bf16x8*>(&Ws[r * 64 + (g ^ (r & 7)) * 8]);
      }
    }
#pragma unroll
    for (int mi = 0; mi < 2; mi++)
#pragma unroll
      for (int nj = 0; nj < 4; nj++) {
        acc[mi][nj] = __builtin_amdgcn_mfma_f32_16x16x32_bf16(
            af[mi][0], bfr[nj][0], acc[mi][nj], 0, 0, 0);
        acc[mi][nj] = __builtin_amdgcn_mfma_f32_16x16x32_bf16(
            af[mi][1], bfr[nj][1], acc[mi][nj], 0, 0, 0);
      }
  }
#pragma unroll
  for (int mi = 0; mi < 2; mi++) {
    int row = m0 + wm * 32 + mi * 16 + lh * 4;
#pragma unroll
    for (int nj = 0; nj < 4; nj++) {
      int col = n0 + wn * 64 + nj * 16 + lr;
      float b = bias[col];
#pragma unroll
      for (int r = 0; r < 4; r++)
        out[(size_t)(row + r) * 256 + col] = acc[mi][nj][r] + b;
    }
  }
}

// ------------- TN GEMM (1x1 lateral conv): A=(B,256,HW) NCHW fp32, W bf16, out bf16 -------------
__global__ __launch_bounds__(256) void gemm_tn_mfma(
    const float* __restrict__ A, const unsigned short* __restrict__ Wb,
    const float* __restrict__ bias, unsigned short* __restrict__ out) {
  __shared__ unsigned short As[64 * 64];
  __shared__ unsigned short Ws[128 * 64];
  const int tid = threadIdx.x;
  const int nwg = gridDim.x;  // 1024
  const int swz = (blockIdx.x & 7) * (nwg >> 3) + (blockIdx.x >> 3);
  const int m0 = (swz >> 1) * 64, n0 = (swz & 1) * 128;
  const int b = m0 >> 14;
  const int p0 = m0 & 16383;
  const int wid = tid >> 6, lane = tid & 63;
  const int wm = wid >> 1, wn = wid & 1;
  const int lr = lane & 15, lh = lane >> 4;
  const int r8 = tid >> 3, g8 = tid & 7;
  const int arow = tid & 63, agb = tid >> 6;  // A mapping: row, granule-base
  f32x4 acc[2][4];
#pragma unroll
  for (int i = 0; i < 2; i++)
#pragma unroll
    for (int j = 0; j < 4; j++) acc[i][j] = f32x4{0.f, 0.f, 0.f, 0.f};

  float va[16];
  uint4 rw[4];
  auto loadA = [&](int k0, float* v) {
#pragma unroll
    for (int i = 0; i < 2; i++) {
      int g = agb + i * 4;
#pragma unroll
      for (int j = 0; j < 8; j++)
        v[i * 8 + j] =
            A[(size_t)(b * 256 + k0 + g * 8 + j) * 16384 + p0 + arow];
    }
  };
  auto loadW = [&](int k0, uint4* r) {
#pragma unroll
    for (int i = 0; i < 4; i++)
      r[i] = *reinterpret_cast<const uint4*>(
          &Wb[(size_t)(n0 + r8 + i * 32) * 256 + k0 + g8 * 8]);
  };
  loadA(0, va);
  loadW(0, rw);

  for (int k0 = 0; k0 < 256; k0 += 64) {
    if (k0) __syncthreads();
#pragma unroll
    for (int i = 0; i < 2; i++)
      store_chunk_f32(As, arow, agb + i * 4, &va[i * 8]);
#pragma unroll
    for (int i = 0; i < 4; i++) store_chunk_bf(Ws, r8 + i * 32, g8, rw[i]);
    __syncthreads();
    int kn = k0 + 64;
    if (kn < 256) {
      loadA(kn, va);
      loadW(kn, rw);
    }
    bf16x8 af[2][2], bfr[4][2];
#pragma unroll
    for (int mi = 0; mi < 2; mi++) {
      int r = wm * 32 + mi * 16 + lr;
#pragma unroll
      for (int s = 0; s < 2; s++) {
        int g = s * 4 + lh;
        af[mi][s] =
            *reinterpret_cast<const bf16x8*>(&As[r * 64 + (g ^ (r & 7)) * 8]);
      }
    }
#pragma unroll
    for (int nj = 0; nj < 4; nj++) {
      int r = wn * 64 + nj * 16 + lr;
#pragma unroll
      for (int s = 0; s < 2; s++) {
        int g = s * 4 + lh;
        bfr[nj][s] =
            *reinterpret_cast<const bf16x8*>(&Ws[r * 64 + (g ^ (r & 7)) * 8]);
      }
    }
#pragma unroll
    for (int mi = 0; mi < 2; mi++)
#pragma unroll
      for (int nj = 0; nj < 4; nj++) {
        acc[mi][nj] = __builtin_amdgcn_mfma_f32_16x16x32_bf16(
            af[mi][0], bfr[nj][0], acc[mi][nj], 0, 0, 0);
        acc[mi][nj] = __builtin_amdgcn_mfma_f32_16x16x32_bf16(
            af[mi][1], bfr[nj][1], acc[mi][nj], 0, 0, 0);
      }
  }
#pragma unroll
  for (int mi = 0; mi < 2; mi++) {
    int row = m0 + wm * 32 + mi * 16 + lh * 4;
#pragma unroll
    for (int nj = 0; nj < 4; nj++) {
      int col = n0 + wn * 64 + nj * 16 + lr;
      float b = bias[col];
#pragma unroll
      for (int r = 0; r < 4; r++)
        out[(size_t)(row + r) * 256 + col] = f2bf(acc[mi][nj][r] + b);
    }
  }
}

// ---------------- MSDA prep: one thread per (b,n,h) ----------------
__global__ __launch_bounds__(256) void msda_prep(
    const float* __restrict__ off, const float* __restrict__ awl,
    float* __restrict__ rec) {
  int gid = blockIdx.x * 256 + threadIdx.x;  // 86016 total
  int h = gid & 7;
  int bn = gid >> 3;
  int n = bn % Ntok;
  int b = bn / Ntok;

  int li0 = (n < 4096) ? 0 : ((n < 5120) ? 1 : 2);
  int start0 = (li0 == 0) ? 0 : ((li0 == 1) ? 4096 : 5120);
  int shift = 6 - li0;
  int Wn = 1 << shift;
  int sp = n - start0;
  int iy = sp >> shift;
  int ix = sp & (Wn - 1);
  float refx = (ix + 0.5f) / (float)Wn;
  float refy = (iy + 0.5f) / (float)Wn;

  const float* ap = awl + (size_t)bn * 96 + h * 12;
  float lg[12];
  float mx = -1e30f;
#pragma unroll
  for (int j = 0; j < 12; j++) { lg[j] = ap[j]; mx = fmaxf(mx, lg[j]); }
  float ssum = 0.f;
#pragma unroll
  for (int j = 0; j < 12; j++) { lg[j] = expf(lg[j] - mx); ssum += lg[j]; }
  float inv = 1.f / ssum;

  const float* op = off + (size_t)bn * 192 + h * 24;
  float* rp = rec + (size_t)gid * 96;
#pragma unroll
  for (int p = 0; p < 12; p++) {
    int li = p >> 2;
    int HWl = 64 >> li;
    int st = (li == 0) ? 0 : ((li == 1) ? 4096 : 5120);
    float ox = op[p * 2 + 0];
    float oy = op[p * 2 + 1];
    float lx = refx + ox / (float)HWl;
    float ly = refy + oy / (float)HWl;
    float fx = lx * (float)HWl - 0.5f;
    float fy = ly * (float)HWl - 0.5f;
    float x0f = floorf(fx), y0f = floorf(fy);
    float wx = fx - x0f, wy = fy - y0f;
    int ix0 = (int)x0f, iy0 = (int)y0f;
    float w = lg[p] * inv;
    int base = (b * Ntok + st) * 256 + h * 32;
    int idx[4];
    float wgt[4];
#pragma unroll
    for (int cr = 0; cr < 4; cr++) {
      int cx = ix0 + (cr & 1);
      int cy = iy0 + (cr >> 1);
      bool valid = (cx >= 0) & (cx < HWl) & (cy >= 0) & (cy < HWl);
      float wc = ((cr & 1) ? wx : 1.f - wx) * ((cr >> 1) ? wy : 1.f - wy);
      int cxc = min(max(cx, 0), HWl - 1);
      int cyc = min(max(cy, 0), HWl - 1);
      idx[cr] = base + (cyc * HWl + cxc) * 256;
      wgt[cr] = valid ? (w * wc) : 0.f;
    }
    *reinterpret_cast<int4*>(rp + p * 8) = int4{idx[0], idx[1], idx[2], idx[3]};
    *reinterpret_cast<float4*>(rp + p * 8 + 4) =
        float4{wgt[0], wgt[1], wgt[2], wgt[3]};
  }
}

// ---------------- MSDA gather ----------------
__global__ __launch_bounds__(256) void msda_gather(
    const unsigned short* __restrict__ value, const float* __restrict__ rec,
    unsigned short* __restrict__ attn) {
  int gid = blockIdx.x * 8 + (threadIdx.x >> 5);
  int lane = threadIdx.x & 31;
  const float* rp = rec + (size_t)gid * 96;
  const unsigned short* vb = value + lane;
  float acc = 0.f;
#pragma unroll
  for (int p = 0; p < 12; p++) {
    int4 idx = *reinterpret_cast<const int4*>(rp + p * 8);
    float4 w = *reinterpret_cast<const float4*>(rp + p * 8 + 4);
    acc += w.x * bf2f(vb[idx.x]);
    acc += w.y * bf2f(vb[idx.y]);
    acc += w.z * bf2f(vb[idx.z]);
    acc += w.w * bf2f(vb[idx.w]);
  }
  attn[(size_t)gid * 32 + lane] = f2bf(acc);
}

// ---------------- residual add + LayerNorm, wave-per-row ----------------
template <int WRITEQ>
__global__ __launch_bounds__(256) void ln_residual(
    float* __restrict__ x, unsigned short* __restrict__ xb,
    const float* __restrict__ r, const float* __restrict__ g,
    const float* __restrict__ bta, const unsigned short* __restrict__ peb,
    unsigned short* __restrict__ qb) {
  int w = threadIdx.x >> 6, lane = threadIdx.x & 63;
  int row = blockIdx.x * 4 + w;
  size_t base = (size_t)row * 256 + lane * 4;
  float4 v = *reinterpret_cast<const float4*>(&x[base]);
  float4 rr = *reinterpret_cast<const float4*>(&r[base]);
  v.x += rr.x; v.y += rr.y; v.z += rr.z; v.w += rr.w;
  float s = v.x + v.y + v.z + v.w;
#pragma unroll
  for (int o = 32; o > 0; o >>= 1) s += __shfl_xor(s, o);
  float mu = s * (1.f / 256.f);
  float4 d = {v.x - mu, v.y - mu, v.z - mu, v.w - mu};
  float sq = d.x * d.x + d.y * d.y + d.z * d.z + d.w * d.w;
#pragma unroll
  for (int o = 32; o > 0; o >>= 1) sq += __shfl_xor(sq, o);
  float rstd = rsqrtf(sq * (1.f / 256.f) + EPSf);
  float4 gv = *reinterpret_cast<const float4*>(&g[lane * 4]);
  float4 bv = *reinterpret_cast<const float4*>(&bta[lane * 4]);
  float4 o4 = {d.x * rstd * gv.x + bv.x, d.y * rstd * gv.y + bv.y,
               d.z * rstd * gv.z + bv.z, d.w * rstd * gv.w + bv.w};
  *reinterpret_cast<float4*>(&x[base]) = o4;
  unsigned short t[4] = {f2bf(o4.x), f2bf(o4.y), f2bf(o4.z), f2bf(o4.w)};
  *reinterpret_cast<uint2*>(&xb[base]) = *reinterpret_cast<const uint2*>(t);
  if (WRITEQ) {
    size_t pc = base - (row >= Ntok ? (size_t)Ntok * 256 : 0);
    ushort4 pv = *reinterpret_cast<const ushort4*>(&peb[pc]);
    unsigned short tq[4] = {
        f2bf(o4.x + bf2f(pv.x)), f2bf(o4.y + bf2f(pv.y)),
        f2bf(o4.z + bf2f(pv.z)), f2bf(o4.w + bf2f(pv.w))};
    *reinterpret_cast<uint2*>(&qb[base]) = *reinterpret_cast<const uint2*>(tq);
  }
}

// ---------------- bilinear 64->128 upsample, += into bf16 t ----------------
__global__ __launch_bounds__(256) void upsample_add(
    const float* __restrict__ xrows, unsigned short* __restrict__ t) {
  int bp = blockIdx.x;
  int c = threadIdx.x;
  int b = bp >> 14;
  int p = bp & 16383;
  int Y = p >> 7, X = p & 127;
  float yc = Y * 0.5f - 0.25f;
  float y0f = floorf(yc);
  float wy = yc - y0f;
  int y0 = (int)y0f, y1 = y0 + 1;
  int y0c = min(max(y0, 0), 63), y1c = min(max(y1, 0), 63);
  float xc = X * 0.5f - 0.25f;
  float x0f = floorf(xc);
  float wx = xc - x0f;
  int xq0 = (int)x0f, xq1 = xq0 + 1;
  int x0c = min(max(xq0, 0), 63), x1c = min(max(xq1, 0), 63);
  const float* base = xrows + (size_t)b * Ntok * 256;
  float v00 = base[(size_t)(y0c * 64 + x0c) * 256 + c];
  float v01 = base[(size_t)(y0c * 64 + x1c) * 256 + c];
  float v10 = base[(size_t)(y1c * 64 + x0c) * 256 + c];
  float v11 = base[(size_t)(y1c * 64 + x1c) * 256 + c];
  float v = (1.f - wy) * ((1.f - wx) * v00 + wx * v01) +
            wy * ((1.f - wx) * v10 + wx * v11);
  size_t idx = (size_t)bp * 256 + c;
  t[idx] = f2bf(bf2f(t[idx]) + v);
}

// ---------------- token rows -> NCHW output (tiled transpose) ----------------
__global__ void rows_to_nchw(const float* __restrict__ xrows,
                             float* __restrict__ out, int start, int size) {
  __shared__ float tile[32][33];
  int p0 = blockIdx.x * 32, c0 = blockIdx.y * 32, b = blockIdx.z;
  int tx = threadIdx.x, tyy = threadIdx.y;
  for (int i = tyy; i < 32; i += 8)
    tile[i][tx] = xrows[((size_t)(b * Ntok + start + p0 + i)) * 256 + c0 + tx];
  __syncthreads();
  for (int i = tyy; i < 32; i += 8)
    out[((size_t)(b * 256 + c0 + i)) * size + p0 + tx] = tile[tx][i];
}

// ---------------- conv weight repack (O,C,3,3) -> bf16 (O, tap*256+c) ----------------
__global__ void wt_transpose(const float* __restrict__ w,
                             unsigned short* __restrict__ wt) {
  for (int i = blockIdx.x * blockDim.x + threadIdx.x; i < 256 * 2304;
       i += gridDim.x * blockDim.x) {
    int o = i / 2304;
    int r = i % 2304;
    int tap = r >> 8;
    int c = r & 255;
    wt[i] = f2bf(w[((size_t)(o * 256 + c)) * 9 + tap]);
  }
}

// ---------------- GroupNorm partial sums ----------------
__global__ __launch_bounds__(256) void gn_partial(
    const float* __restrict__ s, float* __restrict__ part) {
  int blk = blockIdx.x;
  int pr = blk & 15;
  int bg = blk >> 4;
  int g = bg & 31;
  int b = bg >> 5;
  int tid = threadIdx.x;
  float sum = 0.f, sq = 0.f;
  for (int e = pr * 8192 + tid; e < (pr + 1) * 8192; e += 256) {
    int p = e >> 3, cc = e & 7;
    float v = s[((size_t)(b * 16384 + p)) * 256 + g * 8 + cc];
    sum += v;
    sq += v * v;
  }
  __shared__ float rs[256], rq[256];
  rs[tid] = sum;
  rq[tid] = sq;
  __syncthreads();
  for (int st = 128; st > 0; st >>= 1) {
    if (tid < st) { rs[tid] += rs[tid + st]; rq[tid] += rq[tid + st]; }
    __syncthreads();
  }
  if (tid == 0) {
    part[(size_t)blk * 2 + 0] = rs[0];
    part[(size_t)blk * 2 + 1] = rq[0];
  }
}

__global__ void gn_final(const float* __restrict__ part,
                         float* __restrict__ stats) {
  int tid = threadIdx.x;
  if (tid < 64) {
    float s = 0.f, q = 0.f;
    for (int j = 0; j < 16; j++) {
      s += part[(size_t)(tid * 16 + j) * 2 + 0];
      q += part[(size_t)(tid * 16 + j) * 2 + 1];
    }
    float mu = s * (1.f / 131072.f);
    float var = q * (1.f / 131072.f) - mu * mu;
    stats[tid * 2 + 0] = mu;
    stats[tid * 2 + 1] = rsqrtf(var + EPSf);
  }
}

// ---------------- GN apply + GELU + transpose to NCHW ----------------
__global__ void gn_apply(const float* __restrict__ s,
                         const float* __restrict__ stats,
                         const float* __restrict__ gg,
                         const float* __restrict__ gb,
                         float* __restrict__ out) {
  __shared__ float tile[32][33];
  int p0 = blockIdx.x * 32, c0 = blockIdx.y * 32, b = blockIdx.z;
  int tx = threadIdx.x, tyy = threadIdx.y;
  int c = c0 + tx;
  float mu = stats[(b * 32 + (c >> 3)) * 2 + 0];
  float rstd = stats[(b * 32 + (c >> 3)) * 2 + 1];
  float gw = gg[c], bw = gb[c];
  for (int i = tyy; i < 32; i += 8) {
    float v = s[((size_t)(b * 16384 + p0 + i)) * 256 + c];
    v = (v - mu) * rstd * gw + bw;
    v = 0.5f * v * (1.f + erff(v * 0.70710678118654752f));
    tile[i][tx] = v;
  }
  __syncthreads();
  for (int i = tyy; i < 32; i += 8)
    out[((size_t)(b * 256 + c0 + i)) * 16384 + p0 + tx] = tile[tx][i];
}

// ---------------- launcher ----------------
extern "C" void kernel_launch(void* const* d_in, const int* in_sizes, int n_in,
                              void* d_out, int out_size, void* d_ws,
                              size_t ws_size, hipStream_t stream) {
  (void)in_sizes; (void)n_in; (void)out_size; (void)ws_size;
  const float* res2  = (const float*)d_in[0];
  const float* res3  = (const float*)d_in[1];
  const float* res4  = (const float*)d_in[2];
  const float* res5  = (const float*)d_in[3];
  const float* lemb  = (const float*)d_in[4];
  const float* off_W = (const float*)d_in[5];
  const float* off_b = (const float*)d_in[6];
  const float* aw_W  = (const float*)d_in[7];
  const float* aw_b  = (const float*)d_in[8];
  const float* val_W = (const float*)d_in[9];
  const float* val_b = (const float*)d_in[10];
  const float* out_W = (const float*)d_in[11];
  const float* out_b = (const float*)d_in[12];
  const float* ln1_g = (const float*)d_in[13];
  const float* ln1_b = (const float*)d_in[14];
  const float* fc1_W = (const float*)d_in[15];
  const float* fc1_b = (const float*)d_in[16];
  const float* fc2_W = (const float*)d_in[17];
  const float* fc2_b = (const float*)d_in[18];
  const float* ln2_g = (const float*)d_in[19];
  const float* ln2_b = (const float*)d_in[20];
  const float* lat_W = (const float*)d_in[21];
  const float* lat_b = (const float*)d_in[22];
  const float* sm_W  = (const float*)d_in[23];
  const float* sm_b  = (const float*)d_in[24];
  const float* gn_g  = (const float*)d_in[25];
  const float* gn_b  = (const float*)d_in[26];

  float* ws = (float*)d_ws;
  // layout (float units); bf16 buffers take count/2 floats
  float*          x      = ws;                               // (2752512)
  unsigned short* xb     = (unsigned short*)(ws + 2752512);  // (1376256)
  unsigned short* peb    = (unsigned short*)(ws + 4128768);  // (688128)
  unsigned short* qb     = (unsigned short*)(ws + 4816896);  // (1376256)
  unsigned short* valueb = (unsigned short*)(ws + 6193152);  // (1376256)
  float*          offb   = ws + 7569408;                     // (2064384)
  float*          awl    = ws + 9633792;                     // (1032192)
  unsigned short* attnb  = (unsigned short*)(ws + 10665984); // (1376256)
  float*          tmp    = ws + 12042240;                    // (2752512)
  unsigned short* hb     = (unsigned short*)(ws + 14794752); // (5505024)
  unsigned short* tbuf   = hb;  // conv input aliases hb (dead after layers)
  unsigned short* wtbuf  = (unsigned short*)(ws + 20299776); // (294912)
  float*          gnpart = ws + 20594688;                    // (2048)
  float*          gnstat = ws + 20596736;                    // (128)
  unsigned short* wbfu   = (unsigned short*)(ws + 20596864); // (729088 bf16)
  // total 20961408 floats = 83.8 MB
  float*          rec    = tmp;  // aliases tmp+hb (dead in prep..gather window)
  float*          sbuf   = ws;   // conv out fp32 (8388608 f): dead x..offb span

  float* out_s  = (float*)d_out;
  float* out_o3 = out_s + (size_t)Bn * Cc * HW2;
  float* out_o4 = out_o3 + (size_t)Bn * Cc * 4096;
  float* out_o5 = out_o4 + (size_t)Bn * Cc * 1024;

  const int M = Bn * Ntok;  // 10752

  pe_kernel<<<1024, 256, 0, stream>>>(peb);
  flatten_kernel<<<1024, 256, 0, stream>>>(res3, res4, res5, lemb, peb, x, xb,
                                           qb);

  for (int l = 0; l < 6; l++) {
    wconv_layer<<<712, 256, 0, stream>>>(
        val_W + (size_t)l * 65536, off_W + (size_t)l * 49152,
        aw_W + (size_t)l * 24576, out_W + (size_t)l * 65536,
        fc1_W + (size_t)l * 262144, fc2_W + (size_t)l * 262144, wbfu);
    gemm_mfma_b<0, 1><<<336, 256, 0, stream>>>(
        xb, wbfu + 0, val_b + l * 256, valueb, M, 256, 256, 2);
    gemm_offaw<<<504, 256, 0, stream>>>(qb, wbfu + 65536, off_b + l * 192,
                                        aw_b + l * 96, offb, awl, M);
    msda_prep<<<336, 256, 0, stream>>>(offb, awl, rec);
    msda_gather<<<10752, 256, 0, stream>>>(valueb, rec, attnb);
    gemm_mfma_b<0, 0><<<336, 256, 0, stream>>>(
        attnb, wbfu + 139264, out_b + l * 256, tmp, M, 256, 256, 2);
    ln_residual<0><<<M / 4, 256, 0, stream>>>(
        x, xb, tmp, ln1_g + l * 256, ln1_b + l * 256, peb, qb);
    gemm_mfma_b<1, 1><<<1344, 256, 0, stream>>>(
        xb, wbfu + 204800, fc1_b + l * 1024, hb, M, 1024, 256, 8);
    gemm_mfma_b<0, 0><<<336, 256, 0, stream>>>(
        hb, wbfu + 466944, fc2_b + l * 256, tmp, M, 256, 1024, 2);
    ln_residual<1><<<M / 4, 256, 0, stream>>>(
        x, xb, tmp, ln2_g + l * 256, ln2_b + l * 256, peb, qb);
  }

  // token outputs (read x fp32) — must precede sbuf (aliases x) writes
  rows_to_nchw<<<dim3(128, 8, 2), dim3(32, 8), 0, stream>>>(x, out_o3, 0, 4096);
  rows_to_nchw<<<dim3(32, 8, 2), dim3(32, 8), 0, stream>>>(x, out_o4, 4096, 1024);
  rows_to_nchw<<<dim3(8, 8, 2), dim3(32, 8), 0, stream>>>(x, out_o5, 5120, 256);

  // FPN tail
  wconv_flat<<<64, 256, 0, stream>>>(lat_W, wbfu, 16384);
  gemm_tn_mfma<<<1024, 256, 0, stream>>>(res2, wbfu, lat_b, tbuf);
  upsample_add<<<32768, 256, 0, stream>>>(x, tbuf);
  wt_transpose<<<1024, 256, 0, stream>>>(sm_W, wtbuf);
  conv3x3_mfma<<<1024, 256, 0, stream>>>(tbuf, wtbuf, sm_b, sbuf);
  gn_partial<<<1024, 256, 0, stream>>>(sbuf, gnpart);
  gn_final<<<1, 64, 0, stream>>>(gnpart, gnstat);
  gn_apply<<<dim3(512, 8, 2), dim3(32, 8), 0, stream>>>(sbuf, gnstat, gn_g,
                                                        gn_b, out_s);
}